// Round 12
// baseline (369.576 us; speedup 1.0000x reference)
//
#include <hip/hip_runtime.h>
#include <hip/hip_bf16.h>

// Problem constants (B=2, L=2048, D=1024, NH=16, HD=64, H_GATE=256)
constexpr int Bn  = 2;
constexpr int Ln  = 2048;
constexpr int Dn  = 1024;
constexpr int NH  = 16;
constexpr int HGn = 256;
constexpr long BLD = (long)Bn * Ln * Dn;   // 4194304

typedef float f32x4 __attribute__((ext_vector_type(4)));
typedef float f32x2 __attribute__((ext_vector_type(2)));
typedef short s16x8 __attribute__((ext_vector_type(8)));
typedef short s16x4 __attribute__((ext_vector_type(4)));
typedef short s16x2 __attribute__((ext_vector_type(2)));

#define DEVI static __device__ __forceinline__

DEVI float bf2f(short u) {
  union { float f; unsigned int i; } v; v.i = ((unsigned int)(unsigned short)u) << 16; return v.f;
}
DEVI short f2bf(float f) {
  union { float f; unsigned int i; } v; v.f = f;
  unsigned int r = v.i + 0x7FFFu + ((v.i >> 16) & 1u);
  return (short)(r >> 16);
}
DEVI void gl_lds16(const void* g, void* l) {
  __builtin_amdgcn_global_load_lds((const __attribute__((address_space(1))) unsigned int*)g,
                                   (__attribute__((address_space(3))) unsigned int*)l, 16, 0, 0);
}

// ---------------- fused 7-segment cast f32 -> bf16 (dst segments contiguous) ----------------
struct CastDesc { const float* src[7]; long cum[8]; };
__global__ void k_cast7(CastDesc d, short* __restrict__ dst) {
  long gi = ((long)blockIdx.x * 256 + threadIdx.x) * 4;
  int s = 0;
#pragma unroll
  for (int i = 1; i < 7; ++i) if (gi >= d.cum[i]) s = i;
  const float* sp = d.src[s] + (gi - d.cum[s]);
  f32x4 v = *(const f32x4*)sp;
  s16x4 o; o[0] = f2bf(v[0]); o[1] = f2bf(v[1]); o[2] = f2bf(v[2]); o[3] = f2bf(v[3]);
  *(s16x4*)(dst + gi) = o;
}

// ========== T3-minimum 2-phase GEMM: 256x256, BK=64, 8 waves, 1 barrier/iter ==========
// MODE 0: mega projections [Q|K|V|gk|h] = [z|z|z|ps|ps] @ Wcat^T (272 blocks)
// MODE 1: gb = tanh(gamma)/32 * Gk . Kraw^T, causal 256-tiles (72 blocks)
template<int MODE>
__global__ __launch_bounds__(512, 2)
void k_gemm2p(const short* __restrict__ Aall, const short* __restrict__ Ball,
              const short* __restrict__ Wcat,
              const float* __restrict__ bq, const float* __restrict__ bk,
              const float* __restrict__ bv, const float* __restrict__ bg1,
              short* __restrict__ Qp, short* __restrict__ Kp,
              short* __restrict__ Vtb, short* __restrict__ Gk,
              short* __restrict__ Hfb,
              const float* __restrict__ gamma, short* __restrict__ Gb) {
  int m0, n0; const short* Ap; const short* Bp; long cbase = 0;
  if (MODE == 0) {
    int wgid = blockIdx.x;                 // 272 = 8 XCD x (2 m-panels x 17 n-panels)
    int xcd = wgid & 7, idx = wgid >> 3;   // idx 0..33
    n0 = (idx >> 1) * 256;
    m0 = (xcd * 2 + (idx & 1)) * 256;
    Ap = (n0 < 3072) ? Aall : Ball;        // z for Q/K/V, ps for gk/h
    Bp = Wcat;
  } else {
    int tt = blockIdx.x;                   // 72 = 2 batches x 36 causal tiles
    int bz = (tt >= 36) ? 1 : 0; int t6 = tt - bz * 36;
    int qb = 0;
    while ((qb + 1) * (qb + 2) / 2 <= t6) ++qb;
    int kb = t6 - qb * (qb + 1) / 2;
    m0 = qb * 256; n0 = kb * 256;
    Ap = Aall + (long)bz * Ln * Dn;
    Bp = Ball + (long)bz * Ln * Dn;
    cbase = (long)bz * Ln * Ln;
  }
  __shared__ short smA[2][256 * 64];   // 64 KB
  __shared__ short smB[2][256 * 64];   // 64 KB -> 128 KB total, 1 block/CU
  int tid = threadIdx.x, lane = tid & 63, w = tid >> 6;   // 8 waves
  int wr = w >> 2, wc = w & 3;                            // wave tile 128 x 64
  int lr = lane & 15, lg = lane >> 4;
  int tr = tid >> 3, tc = (tid & 7) * 8;                  // staging row (0..63), col
  f32x4 acc[8][4] = {};
  auto stage = [&](int buf, int t) {
    const short* As = Ap + (long)m0 * Dn + t * 64;
    const short* Bs = Bp + (long)n0 * Dn + t * 64;
#pragma unroll
    for (int j = 0; j < 4; ++j) {
      gl_lds16(As + (long)(j * 64 + tr) * Dn + tc, &smA[buf][(j * 64 + tr) * 64 + tc]);
      gl_lds16(Bs + (long)(j * 64 + tr) * Dn + tc, &smB[buf][(j * 64 + tr) * 64 + tc]);
    }
  };
  stage(0, 0);
  asm volatile("s_waitcnt vmcnt(0)" ::: "memory");
  __builtin_amdgcn_s_barrier();
  int cur = 0;
  for (int t = 0; t < 16; ++t) {
    if (t + 1 < 16) stage(cur ^ 1, t + 1);   // issue next-tile loads FIRST
    const short* Abase = &smA[cur][(wr * 128 + lr) * 64];
    const short* Bbase = &smB[cur][(wc * 64 + lr) * 64];
    s16x8 af[2][8], bfr[2][4];
#pragma unroll
    for (int ks = 0; ks < 2; ++ks) {
#pragma unroll
      for (int m = 0; m < 8; ++m) af[ks][m] = *(const s16x8*)(Abase + m * 16 * 64 + ks * 32 + lg * 8);
#pragma unroll
      for (int n = 0; n < 4; ++n) bfr[ks][n] = *(const s16x8*)(Bbase + n * 16 * 64 + ks * 32 + lg * 8);
    }
    asm volatile("s_waitcnt lgkmcnt(0)" ::: "memory");
    __builtin_amdgcn_sched_barrier(0);
    __builtin_amdgcn_s_setprio(1);
#pragma unroll
    for (int ks = 0; ks < 2; ++ks)
#pragma unroll
      for (int m = 0; m < 8; ++m)
#pragma unroll
        for (int n = 0; n < 4; ++n)
          acc[m][n] = __builtin_amdgcn_mfma_f32_16x16x32_bf16(af[ks][m], bfr[ks][n], acc[m][n], 0, 0, 0);
    __builtin_amdgcn_s_setprio(0);
    asm volatile("s_waitcnt vmcnt(0)" ::: "memory");   // drains loads issued ONE iter ago
    __builtin_amdgcn_s_barrier();                      // single barrier per iteration
    cur ^= 1;
  }
  if (MODE == 0) {
    int slice = n0 >> 10;   // 0..4 (4352 cols; h-tile is exactly n0=4096)
#pragma unroll
    for (int n = 0; n < 4; n++) {
      int col = n0 + wc * 64 + n * 16 + lr;
      int c = col - (slice << 10);
      float bias = (slice == 0) ? bq[c] : (slice == 1) ? bk[c] : (slice == 2) ? bv[c]
                 : (slice == 3) ? 0.0f : bg1[c];
#pragma unroll
      for (int m = 0; m < 8; m++) {
#pragma unroll
        for (int r = 0; r < 4; r++) {
          long row = m0 + wr * 128 + m * 16 + lg * 4 + r;
          float v = acc[m][n][r] + bias;
          if (slice == 4) {
            v = 0.5f * v * (1.0f + erff(v * 0.70710678118f));
            Hfb[row * HGn + c] = f2bf(v);
          } else if (slice == 2) {
            long off = (((row >> 11) * (long)NH + (c >> 6)) * 64 + (c & 63)) * Ln + (row & (Ln - 1));
            Vtb[off] = f2bf(v);
          } else {
            short* dst = (slice == 0) ? Qp : (slice == 1) ? Kp : Gk;
            dst[row * (long)Dn + c] = f2bf(v);
          }
        }
      }
    }
  } else {
    float alpha = tanhf(gamma[0]) * 0.03125f;
#pragma unroll
    for (int n = 0; n < 4; n++) {
      int col = n0 + wc * 64 + n * 16 + lr;
#pragma unroll
      for (int m = 0; m < 8; m++) {
#pragma unroll
        for (int r = 0; r < 4; r++) {
          long row = m0 + wr * 128 + m * 16 + lg * 4 + r;
          Gb[cbase + row * Ln + col] = f2bf(acc[m][n][r] * alpha);
        }
      }
    }
  }
}

// ---------------- RoPE cos/sin tables: [L][512] for both bases ----------------
__global__ void k_rope_tables(float* __restrict__ ctf, float* __restrict__ stf,
                              float* __restrict__ cts, float* __restrict__ sts) {
  int idx = blockIdx.x * 256 + threadIdx.x;   // L*512 total
  int l = idx >> 9, j = idx & 511;
  float e = (float)j * (1.0f / 512.0f);
  float invf = powf(1.6180339887498949f, -e);
  float invs = powf(1618.0f, -e);
  float af = (float)l * invf, as = (float)l * invs;
  float sf, cf, ss, cs;
  sincosf(af, &sf, &cf);
  sincosf(as, &ss, &cs);
  ctf[idx] = cf; stf[idx] = sf; cts[idx] = cs; sts[idx] = ss;
}

// ---------------- gate = sigmoid(h . Wg2 + bg2), one wave per row (h in bf16) ----------------
__global__ void k_gate(const short* __restrict__ Hfb, const float* __restrict__ Wg2,
                       const float* __restrict__ bg2, float* __restrict__ gate) {
  int lane = threadIdx.x & 63, wid = threadIdx.x >> 6;
  int row = blockIdx.x * 4 + wid;
  s16x4 h4 = *(const s16x4*)(Hfb + (long)row * HGn + lane * 4);
  f32x4 w = *(const f32x4*)(Wg2 + lane * 4);
  float s = bf2f(h4[0]) * w[0] + bf2f(h4[1]) * w[1] + bf2f(h4[2]) * w[2] + bf2f(h4[3]) * w[3];
#pragma unroll
  for (int m = 1; m < 64; m <<= 1) s += __shfl_xor(s, m);
  if (lane == 0) gate[row] = 1.0f / (1.0f + __expf(-(s + bg2[0])));
}

// ---------------- RoPE apply (in place, Q and K), one block per (b,l) ----------------
__global__ void k_rope(short* __restrict__ Q, short* __restrict__ Kx,
                       const float* __restrict__ gate,
                       const float* __restrict__ ctf, const float* __restrict__ stf,
                       const float* __restrict__ cts, const float* __restrict__ sts) {
  int bl = blockIdx.x;
  int l = bl & (Ln - 1);
  int t = threadIdx.x;
  float g = gate[bl];
  int j = t * 2;
  f32x2 vcf = *(const f32x2*)(ctf + l * 512 + j);
  f32x2 vsf = *(const f32x2*)(stf + l * 512 + j);
  f32x2 vcs = *(const f32x2*)(cts + l * 512 + j);
  f32x2 vss = *(const f32x2*)(sts + l * 512 + j);
  float c0 = g * vcf[0] + (1.f - g) * vcs[0];
  float c1 = g * vcf[1] + (1.f - g) * vcs[1];
  float s0 = g * vsf[0] + (1.f - g) * vss[0];
  float s1 = g * vsf[1] + (1.f - g) * vss[1];
  long base = (long)bl * Dn + j;
  {
    s16x2 xa = *(const s16x2*)(Q + base);
    s16x2 xb = *(const s16x2*)(Q + base + 512);
    float a0 = bf2f(xa[0]), a1 = bf2f(xa[1]), b0 = bf2f(xb[0]), b1 = bf2f(xb[1]);
    s16x2 o0, o1;
    o0[0] = f2bf(a0 * c0 - b0 * s0); o0[1] = f2bf(a1 * c1 - b1 * s1);
    o1[0] = f2bf(b0 * c0 + a0 * s0); o1[1] = f2bf(b1 * c1 + a1 * s1);
    *(s16x2*)(Q + base) = o0;
    *(s16x2*)(Q + base + 512) = o1;
  }
  {
    s16x2 xa = *(const s16x2*)(Kx + base);
    s16x2 xb = *(const s16x2*)(Kx + base + 512);
    float a0 = bf2f(xa[0]), a1 = bf2f(xa[1]), b0 = bf2f(xb[0]), b1 = bf2f(xb[1]);
    s16x2 o0, o1;
    o0[0] = f2bf(a0 * c0 - b0 * s0); o0[1] = f2bf(a1 * c1 - b1 * s1);
    o1[0] = f2bf(b0 * c0 + a0 * s0); o1[1] = f2bf(b1 * c1 + a1 * s1);
    *(s16x2*)(Kx + base) = o0;
    *(s16x2*)(Kx + base + 512) = o1;
  }
}

// ---------------- attention pass 1: uniform-work pairs (qb, 31-qb), XCD-grouped ----------------
__global__ __launch_bounds__(256)
void k_attn1(const short* __restrict__ Q, const short* __restrict__ Kx,
             const short* __restrict__ Vt, const short* __restrict__ Gb,
             float* __restrict__ outp, float* __restrict__ zinv) {
  int wg = blockIdx.x;              // 0..511
  int xcd = wg & 7, slot = wg >> 3; // slot 0..63
  int p = slot & 15, gh = slot >> 4;
  int g = gh * 8 + xcd;             // 0..31 (b,h) group
  int b = g >> 4, h = g & 15;

  int tid = threadIdx.x;
  int lane = tid & 63, w = tid >> 6;
  int lr = lane & 15, lg = lane >> 4;
  __shared__ short smK[2][64 * 64];
  __shared__ short smV[2][64 * 64];
  __shared__ short smP[4 * 16 * 64];
  short* pw = smP + w * 1024;

  int r0 = w * 16 + (lane >> 3);                 // staged row in tile (0..63)
  int scol = ((lane & 7) ^ (lane >> 3)) * 8;     // pre-swizzled source col (elems)
  const short* Kg = Kx + (long)(b * Ln) * Dn + h * 64;
  const short* Vg = Vt + (long)(b * NH + h) * 64 * Ln;
  int sw = (lr & 7) << 3;                        // read-side XOR (elems)

  for (int seg = 0; seg < 2; ++seg) {
    int qb = seg ? (31 - p) : p;
    int q0w = qb * 64 + w * 16;
    const short* qbp = Q + ((long)(b * Ln) + q0w + lr) * Dn + h * 64 + lg * 8;
    s16x8 qf0 = *(const s16x8*)(qbp);
    s16x8 qf1 = *(const s16x8*)(qbp + 32);
    f32x4 acc[4] = {};
    float az[4] = {0.f, 0.f, 0.f, 0.f};
    const short* gbase = Gb + ((long)b * Ln + q0w + lg * 4) * Ln + lr;

    int nt = qb + 1;
    auto stage = [&](int buf, int t) {
      long k0 = (long)t * 64;
      short* bK = &smK[buf][w * 1024];
      short* bV = &smV[buf][w * 1024];
      gl_lds16(Kg + (k0 + r0) * Dn + scol,           bK);
      gl_lds16(Kg + (k0 + r0 + 8) * Dn + scol,       bK + 512);
      gl_lds16(Vg + (long)r0 * Ln + k0 + scol,       bV);
      gl_lds16(Vg + (long)(r0 + 8) * Ln + k0 + scol, bV + 512);
    };

    float gcur[4][4], gnxt[4][4];
    stage(0, 0);
    {
      const short* g0 = gbase;
#pragma unroll
      for (int kk = 0; kk < 4; ++kk)
#pragma unroll
        for (int r = 0; r < 4; ++r) gcur[kk][r] = bf2f(g0[(long)r * Ln + kk * 16]);
    }
    int cur = 0;
    for (int t = 0; t < nt; ++t) {
      bool pre = (t + 1 < nt);
      if (pre) {
        const short* g0 = gbase + (t + 1) * 64;
#pragma unroll
        for (int kk = 0; kk < 4; ++kk)
#pragma unroll
          for (int r = 0; r < 4; ++r) gnxt[kk][r] = bf2f(g0[(long)r * Ln + kk * 16]);
        stage(cur ^ 1, t + 1);
      }
      __builtin_amdgcn_sched_barrier(0);
      if (pre) asm volatile("s_waitcnt vmcnt(20)" ::: "memory");
      else     asm volatile("s_waitcnt vmcnt(0)" ::: "memory");
      __builtin_amdgcn_s_barrier();
      __builtin_amdgcn_sched_barrier(0);
      int k0 = t * 64;
      const short* Kc = smK[cur];
      const short* Vc = smV[cur];
#pragma unroll
      for (int kk = 0; kk < 4; ++kk) {
        const short* kr = Kc + (kk * 16 + lr) * 64;
        s16x8 kf0 = *(const s16x8*)(kr + ((lg * 8) ^ sw));
        s16x8 kf1 = *(const s16x8*)(kr + ((32 + lg * 8) ^ sw));
        f32x4 S = {};
        S = __builtin_amdgcn_mfma_f32_16x16x32_bf16(qf0, kf0, S, 0, 0, 0);
        S = __builtin_amdgcn_mfma_f32_16x16x32_bf16(qf1, kf1, S, 0, 0, 0);
        int k = k0 + kk * 16 + lr;
#pragma unroll
        for (int r = 0; r < 4; r++) {
          int q = q0w + lg * 4 + r;
          float arg = (k <= q) ? (S[r] * 0.125f + gcur[kk][r]) : -80.0f;
          float pv = __expf(arg);
          az[r] += pv;
          int qq = lg * 4 + r;
          pw[qq * 64 + ((kk * 16 + lr) ^ ((qq & 7) << 3))] = f2bf(pv);
        }
      }
#pragma unroll
      for (int c = 0; c < 2; ++c) {
        s16x8 pf = *(const s16x8*)(pw + lr * 64 + ((c * 32 + lg * 8) ^ sw));
#pragma unroll
        for (int n = 0; n < 4; n++) {
          s16x8 vf = *(const s16x8*)(Vc + (n * 16 + lr) * 64 + ((c * 32 + lg * 8) ^ sw));
          acc[n] = __builtin_amdgcn_mfma_f32_16x16x32_bf16(pf, vf, acc[n], 0, 0, 0);
        }
      }
      __builtin_amdgcn_s_barrier();
      if (pre) {
#pragma unroll
        for (int kk = 0; kk < 4; ++kk)
#pragma unroll
          for (int r = 0; r < 4; ++r) gcur[kk][r] = gnxt[kk][r];
      }
      cur ^= 1;
    }
#pragma unroll
    for (int r = 0; r < 4; r++) {
      float z = az[r];
      z += __shfl_xor(z, 1); z += __shfl_xor(z, 2); z += __shfl_xor(z, 4); z += __shfl_xor(z, 8);
      az[r] = 1.0f / z;
    }
    if (lr == 0) {
#pragma unroll
      for (int r = 0; r < 4; r++)
        zinv[((long)(b * NH + h)) * Ln + q0w + lg * 4 + r] = az[r];
    }
#pragma unroll
    for (int n = 0; n < 4; n++) {
#pragma unroll
      for (int r = 0; r < 4; r++) {
        int q = q0w + lg * 4 + r;
        outp[((long)(b * Ln) + q) * Dn + h * 64 + n * 16 + lr] = acc[n][r] * az[r];
      }
    }
  }
}

// ---------------- attention pass 2: full 64x64 tile grid; upper tiles write zeros ----------------
__global__ __launch_bounds__(256)
void k_attn2(const short* __restrict__ Qm, const short* __restrict__ Kx,
             const short* __restrict__ Gb, const float* __restrict__ zinv, float* __restrict__ aw) {
  int b = blockIdx.y;
  int t = blockIdx.x;
  int qb = t >> 5, kb = t & 31;
  int q0 = qb * 64, k0 = kb * 64;
  int tid = threadIdx.x;
  if (kb > qb) {   // strict upper tile: zero-fill
    int row = tid >> 2, c4 = (tid & 3) << 4;
    float* basep = aw + ((long)b * Ln + q0 + row) * Ln + k0 + c4;
    f32x4 z = {};
    *(f32x4*)(basep) = z; *(f32x4*)(basep + 4) = z;
    *(f32x4*)(basep + 8) = z; *(f32x4*)(basep + 12) = z;
    return;
  }
  int lane = tid & 63, w = tid >> 6;
  int lr = lane & 15, lg = lane >> 4;
  int q0w = q0 + w * 16;
  bool diag = (qb == kb);
  __shared__ short smK[2][64 * 64];
  __shared__ short smQ[2][64 * 64];
  __shared__ float smZ[NH * 64];
  for (int i = tid; i < NH * 64; i += 256) {
    int h = i >> 6, qq = i & 63;
    smZ[i] = zinv[((long)(b * NH + h)) * Ln + q0 + qq];
  }
  __syncthreads();
  float gv[4][4];
#pragma unroll
  for (int n = 0; n < 4; n++) {
    int k = k0 + n * 16 + lr;
#pragma unroll
    for (int r = 0; r < 4; r++)
      gv[n][r] = bf2f(Gb[((long)b * Ln + q0w + lg * 4 + r) * Ln + k]);
  }
  int r0 = w * 16 + (lane >> 3);
  int scol = ((lane & 7) ^ (lane >> 3)) * 8;
  int sw = (lr & 7) << 3;
  auto stage = [&](int buf, int h) {
    short* bK = &smK[buf][w * 1024];
    short* bQ = &smQ[buf][w * 1024];
    const short* Kg = Kx + ((long)(b * Ln) + k0 + r0) * Dn + h * 64 + scol;
    gl_lds16(Kg, bK);
    gl_lds16(Kg + 8 * Dn, bK + 512);
    const short* Qg = Qm + ((long)(b * Ln) + q0 + r0) * Dn + h * 64 + scol;
    gl_lds16(Qg, bQ);
    gl_lds16(Qg + 8 * Dn, bQ + 512);
  };
  float wa[4][4] = {{0.f}};
  stage(0, 0);
  int cur = 0;
  for (int h = 0; h < NH; ++h) {
    bool pre = (h + 1 < NH);
    if (pre) stage(cur ^ 1, h + 1);
    __builtin_amdgcn_sched_barrier(0);
    if (pre) asm volatile("s_waitcnt vmcnt(4)" ::: "memory");
    else     asm volatile("s_waitcnt vmcnt(0)" ::: "memory");
    __builtin_amdgcn_s_barrier();
    __builtin_amdgcn_sched_barrier(0);
    const short* Kc = smK[cur];
    const short* Qc = smQ[cur];
    s16x8 qf0 = *(const s16x8*)(Qc + (w * 16 + lr) * 64 + ((lg * 8) ^ sw));
    s16x8 qf1 = *(const s16x8*)(Qc + (w * 16 + lr) * 64 + ((32 + lg * 8) ^ sw));
    float zq[4];
#pragma unroll
    for (int r = 0; r < 4; r++) zq[r] = smZ[h * 64 + w * 16 + lg * 4 + r];
#pragma unroll
    for (int n = 0; n < 4; n++) {
      const short* kr = Kc + (n * 16 + lr) * 64;
      s16x8 kf0 = *(const s16x8*)(kr + ((lg * 8) ^ sw));
      s16x8 kf1 = *(const s16x8*)(kr + ((32 + lg * 8) ^ sw));
      f32x4 S = {};
      S = __builtin_amdgcn_mfma_f32_16x16x32_bf16(qf0, kf0, S, 0, 0, 0);
      S = __builtin_amdgcn_mfma_f32_16x16x32_bf16(qf1, kf1, S, 0, 0, 0);
#pragma unroll
      for (int r = 0; r < 4; r++)
        wa[n][r] += __expf(S[r] * 0.125f + gv[n][r]) * zq[r];
    }
    __builtin_amdgcn_s_barrier();
    cur ^= 1;
  }
#pragma unroll
  for (int n = 0; n < 4; n++) {
    int k = k0 + n * 16 + lr;
#pragma unroll
    for (int r = 0; r < 4; r++) {
      int q = q0w + lg * 4 + r;
      float v = wa[n][r] * (1.0f / 16.0f);
      if (diag && k > q) v = 0.0f;
      aw[((long)b * Ln + q) * Ln + k] = v;
    }
  }
}

extern "C" void kernel_launch(void* const* d_in, const int* in_sizes, int n_in,
                              void* d_out, int out_size, void* d_ws, size_t ws_size,
                              hipStream_t stream) {
  const float* z    = (const float*)d_in[0];
  const float* ps   = (const float*)d_in[1];
  const float* Wq   = (const float*)d_in[2];
  const float* bq   = (const float*)d_in[3];
  const float* Wk   = (const float*)d_in[4];
  const float* bk   = (const float*)d_in[5];
  const float* Wv   = (const float*)d_in[6];
  const float* bv   = (const float*)d_in[7];
  const float* Wc   = (const float*)d_in[8];
  const float* gamma= (const float*)d_in[9];
  const float* Wg1  = (const float*)d_in[10];
  const float* bg1  = (const float*)d_in[11];
  const float* Wg2  = (const float*)d_in[12];
  const float* bg2  = (const float*)d_in[13];

  char* w = (char*)d_ws;
  auto alloc = [&](long bytes) { void* p = (void*)w; w += (bytes + 255) & ~255L; return p; };
  short* zb   = (short*)alloc(BLD * 2);                   // dead after mega GEMM
  short* pb   = (short*)alloc(BLD * 2);                   // dead after mega GEMM
  short* Wcat = (short*)alloc((long)(4 * Dn + HGn) * Dn * 2);
  short* Qp   = (short*)alloc(BLD * 2);
  short* Kp   = (short*)alloc(BLD * 2);
  short* Vtb  = (short*)alloc(BLD * 2);                   // V transposed: [b][h][d][L]
  short* Gk   = (short*)alloc(BLD * 2);
  short* Hfb  = (short*)alloc((long)Bn * Ln * HGn * 2);   // h in bf16
  float* gate = (float*)alloc((long)Bn * Ln * 4);
  float* ctf  = (float*)alloc((long)Ln * 512 * 4);
  float* stf  = (float*)alloc((long)Ln * 512 * 4);
  float* cts  = (float*)alloc((long)Ln * 512 * 4);
  float* sts  = (float*)alloc((long)Ln * 512 * 4);
  float* zv   = (float*)alloc((long)Bn * NH * Ln * 4);
  short* Gb   = (short*)zb;   // 16.8MB bias slab aliases zb+pb (dead by then)

  float* outp = (float*)d_out;
  float* aw   = outp + BLD;

  // 1) fused casts (dst = zb|pb|Wcat contiguous)
  CastDesc cd;
  cd.src[0] = z;  cd.src[1] = ps; cd.src[2] = Wq; cd.src[3] = Wk;
  cd.src[4] = Wv; cd.src[5] = Wc; cd.src[6] = Wg1;
  long c0 = 0;
  cd.cum[0] = 0;
  cd.cum[1] = (c0 += BLD);
  cd.cum[2] = (c0 += BLD);
  cd.cum[3] = (c0 += (long)Dn * Dn);
  cd.cum[4] = (c0 += (long)Dn * Dn);
  cd.cum[5] = (c0 += (long)Dn * Dn);
  cd.cum[6] = (c0 += (long)Dn * Dn);
  cd.cum[7] = (c0 += (long)HGn * Dn);
  k_cast7<<<(int)(c0 / 1024), 256, 0, stream>>>(cd, zb);

  // 2) merged projections — T3-minimum 2-phase 256²/BK=64
  k_gemm2p<0><<<272, 512, 0, stream>>>(zb, pb, Wcat, bq, bk, bv, bg1,
                                       Qp, Kp, Vtb, Gk, Hfb, nullptr, nullptr);

  // 3) gb (bf16, causal 256-tiles) — same template
  k_gemm2p<1><<<72, 512, 0, stream>>>(Gk, Kp, nullptr, nullptr, nullptr, nullptr, nullptr,
                                      nullptr, nullptr, nullptr, nullptr, nullptr, gamma, Gb);

  // 4) RoPE tables, gate, in-place rotation of Q/K (K raw already consumed by gb)
  k_rope_tables<<<(Ln * 512) / 256, 256, 0, stream>>>(ctf, stf, cts, sts);
  k_gate<<<(Bn * Ln) / 4, 256, 0, stream>>>(Hfb, Wg2, bg2, gate);
  k_rope<<<Bn * Ln, 256, 0, stream>>>(Qp, Kp, gate, ctf, stf, cts, sts);

  // 5) attention
  k_attn1<<<512, 256, 0, stream>>>(Qp, Kp, Vtb, Gb, outp, zv);
  k_attn2<<<dim3(32 * 32, Bn), 256, 0, stream>>>(Qp, Kp, Gb, zv, aw);
}

// Round 13
// 233.312 us; speedup vs baseline: 1.5840x; 1.5840x over previous
//
#include <hip/hip_runtime.h>
#include <hip/hip_bf16.h>

// Problem constants (B=2, L=2048, D=1024, NH=16, HD=64, H_GATE=256)
constexpr int Bn  = 2;
constexpr int Ln  = 2048;
constexpr int Dn  = 1024;
constexpr int NH  = 16;
constexpr int HGn = 256;
constexpr long BLD = (long)Bn * Ln * Dn;   // 4194304

typedef float f32x4 __attribute__((ext_vector_type(4)));
typedef float f32x2 __attribute__((ext_vector_type(2)));
typedef short s16x8 __attribute__((ext_vector_type(8)));
typedef short s16x4 __attribute__((ext_vector_type(4)));
typedef short s16x2 __attribute__((ext_vector_type(2)));

#define DEVI static __device__ __forceinline__

DEVI float bf2f(short u) {
  union { float f; unsigned int i; } v; v.i = ((unsigned int)(unsigned short)u) << 16; return v.f;
}
DEVI short f2bf(float f) {
  union { float f; unsigned int i; } v; v.f = f;
  unsigned int r = v.i + 0x7FFFu + ((v.i >> 16) & 1u);
  return (short)(r >> 16);
}
DEVI void gl_lds16(const void* g, void* l) {
  __builtin_amdgcn_global_load_lds((const __attribute__((address_space(1))) unsigned int*)g,
                                   (__attribute__((address_space(3))) unsigned int*)l, 16, 0, 0);
}

// ---------------- fused 7-segment cast f32 -> bf16 (dst segments contiguous) ----------------
struct CastDesc { const float* src[7]; long cum[8]; };
__global__ void k_cast7(CastDesc d, short* __restrict__ dst) {
  long gi = ((long)blockIdx.x * 256 + threadIdx.x) * 4;
  int s = 0;
#pragma unroll
  for (int i = 1; i < 7; ++i) if (gi >= d.cum[i]) s = i;
  const float* sp = d.src[s] + (gi - d.cum[s]);
  f32x4 v = *(const f32x4*)sp;
  s16x4 o; o[0] = f2bf(v[0]); o[1] = f2bf(v[1]); o[2] = f2bf(v[2]); o[3] = f2bf(v[3]);
  *(s16x4*)(dst + gi) = o;
}

// ---------------- merged projection GEMM: 128x128, BK=32, dbuf, REGISTER-DIET ----------------
// K=1024 places this on the m102 short-K curve (~250 TF family floor) — accepted.
__global__ __launch_bounds__(256, 4)
void k_gemm_mega(const short* __restrict__ zb, const short* __restrict__ pb,
                 const short* __restrict__ Wcat,
                 const float* __restrict__ bq, const float* __restrict__ bk,
                 const float* __restrict__ bv, const float* __restrict__ bg1,
                 short* __restrict__ Qp, short* __restrict__ Kp,
                 short* __restrict__ Vtb, short* __restrict__ Gk,
                 short* __restrict__ Hfb) {
  int wgid = blockIdx.x;
  int xcd = wgid & 7, idx = wgid >> 3;      // idx 0..135
  int n0 = (idx >> 2) * 128;
  int m0 = (xcd * 4 + (idx & 3)) * 128;
  const short* Ap = (n0 < 3072) ? zb : pb;
  __shared__ short smA[2][128 * 32];
  __shared__ short smB[2][128 * 32];
  int tid = threadIdx.x;
  int lane = tid & 63, wid = tid >> 6;
  int wr = wid >> 1, wc = wid & 1;
  int lr = lane & 15, lg = lane >> 4;
  int r_in = lane >> 2;
  int slot = (lane & 3) * 8;
  int scol = ((lane & 3) ^ ((lane >> 3) & 3)) * 8;
  int rsw = (lr >> 1) & 3;
  f32x4 acc[4][4] = {};
  auto stage = [&](int buf, int k0) {
    int rowA = wid * 32 + r_in;
    gl_lds16(Ap   + (long)(m0 + rowA)      * Dn + k0 + scol, &smA[buf][rowA * 32 + slot]);
    gl_lds16(Ap   + (long)(m0 + rowA + 16) * Dn + k0 + scol, &smA[buf][(rowA + 16) * 32 + slot]);
    gl_lds16(Wcat + (long)(n0 + rowA)      * Dn + k0 + scol, &smB[buf][rowA * 32 + slot]);
    gl_lds16(Wcat + (long)(n0 + rowA + 16) * Dn + k0 + scol, &smB[buf][(rowA + 16) * 32 + slot]);
  };
  stage(0, 0);
  int cur = 0;
  for (int k0 = 0; k0 < Dn; k0 += 32) {
    bool pre = (k0 + 32 < Dn);
    if (pre) stage(cur ^ 1, k0 + 32);
    __builtin_amdgcn_sched_barrier(0);
    if (pre) asm volatile("s_waitcnt vmcnt(4)" ::: "memory");
    else     asm volatile("s_waitcnt vmcnt(0)" ::: "memory");
    __builtin_amdgcn_s_barrier();
    __builtin_amdgcn_sched_barrier(0);
    const short* Ab = &smA[cur][(wr * 64 + lr) * 32 + ((lg ^ rsw) * 8)];
    const short* Bb = &smB[cur][(wc * 64 + lr) * 32 + ((lg ^ rsw) * 8)];
    s16x8 b0 = *(const s16x8*)(Bb);
    s16x8 b1 = *(const s16x8*)(Bb + 16 * 32);
    s16x8 b2 = *(const s16x8*)(Bb + 32 * 32);
    s16x8 b3 = *(const s16x8*)(Bb + 48 * 32);
#pragma unroll
    for (int m = 0; m < 4; m++) {
      s16x8 a = *(const s16x8*)(Ab + m * 16 * 32);
      acc[m][0] = __builtin_amdgcn_mfma_f32_16x16x32_bf16(a, b0, acc[m][0], 0, 0, 0);
      acc[m][1] = __builtin_amdgcn_mfma_f32_16x16x32_bf16(a, b1, acc[m][1], 0, 0, 0);
      acc[m][2] = __builtin_amdgcn_mfma_f32_16x16x32_bf16(a, b2, acc[m][2], 0, 0, 0);
      acc[m][3] = __builtin_amdgcn_mfma_f32_16x16x32_bf16(a, b3, acc[m][3], 0, 0, 0);
    }
    __builtin_amdgcn_s_barrier();
    cur ^= 1;
  }
  int slice = n0 >> 10;   // 0..4 (4352 cols)
#pragma unroll
  for (int n = 0; n < 4; n++) {
    int col = n0 + wc * 64 + n * 16 + lr;
    int c = col - (slice << 10);
    float bias = (slice == 0) ? bq[c] : (slice == 1) ? bk[c] : (slice == 2) ? bv[c]
               : (slice == 3) ? 0.0f : bg1[c];
#pragma unroll
    for (int m = 0; m < 4; m++) {
#pragma unroll
      for (int r = 0; r < 4; r++) {
        long row = m0 + wr * 64 + m * 16 + lg * 4 + r;
        float v = acc[m][n][r] + bias;
        if (slice == 4) {
          v = 0.5f * v * (1.0f + erff(v * 0.70710678118f));
          Hfb[row * HGn + c] = f2bf(v);
        } else if (slice == 2) {
          long off = (((row >> 11) * (long)NH + (c >> 6)) * 64 + (c & 63)) * Ln + (row & (Ln - 1));
          Vtb[off] = f2bf(v);
        } else {
          short* dst = (slice == 0) ? Qp : (slice == 1) ? Kp : Gk;
          dst[row * (long)Dn + c] = f2bf(v);
        }
      }
    }
  }
}

// ---------------- gb GEMM: Gb[b,q,k] = bf16( tanh(gamma)/32 * gk[q].K_raw[k] ), triangular grid ----------------
__global__ __launch_bounds__(256)
void k_gemm_gb(const short* __restrict__ A, const short* __restrict__ B,
               const float* __restrict__ gamma, short* __restrict__ C) {
  int bz = blockIdx.y;
  int t0 = blockIdx.x;
  int qb = (int)((sqrtf(8.0f * (float)t0 + 1.0f) - 1.0f) * 0.5f);
  while ((qb + 1) * (qb + 2) / 2 <= t0) ++qb;
  while (qb * (qb + 1) / 2 > t0) --qb;
  int kb = t0 - qb * (qb + 1) / 2;
  int m0 = qb * 128, n0 = kb * 128;
  const short* Ap = A + (long)bz * Ln * Dn;
  const short* Bp = B + (long)bz * Ln * Dn;
  __shared__ short smA[3][128 * 32];
  __shared__ short smB[3][128 * 32];
  int tid = threadIdx.x;
  int lane = tid & 63, wid = tid >> 6;
  int wr = wid >> 1, wc = wid & 1;
  int lr = lane & 15, lg = lane >> 4;
  int r_in = lane >> 2;
  int slot = (lane & 3) * 8;
  int scol = ((lane & 3) ^ ((lane >> 3) & 3)) * 8;
  int rsw = (lr >> 1) & 3;
  f32x4 acc[4][4] = {};
  auto stage = [&](int buf, int k0) {
    int rowA = wid * 32 + r_in;
    gl_lds16(Ap + (long)(m0 + rowA)      * Dn + k0 + scol, &smA[buf][rowA * 32 + slot]);
    gl_lds16(Ap + (long)(m0 + rowA + 16) * Dn + k0 + scol, &smA[buf][(rowA + 16) * 32 + slot]);
    gl_lds16(Bp + (long)(n0 + rowA)      * Dn + k0 + scol, &smB[buf][rowA * 32 + slot]);
    gl_lds16(Bp + (long)(n0 + rowA + 16) * Dn + k0 + scol, &smB[buf][(rowA + 16) * 32 + slot]);
  };
  stage(0, 0);
  stage(1, 32);
  int cur = 0, sb = 2;
  for (int t = 0; t < 32; ++t) {
    if (t + 2 < 32) stage(sb, (t + 2) * 32);
    __builtin_amdgcn_sched_barrier(0);
    int rem = 31 - t;
    if (rem >= 2)      asm volatile("s_waitcnt vmcnt(8)" ::: "memory");
    else if (rem == 1) asm volatile("s_waitcnt vmcnt(4)" ::: "memory");
    else               asm volatile("s_waitcnt vmcnt(0)" ::: "memory");
    __builtin_amdgcn_s_barrier();
    __builtin_amdgcn_sched_barrier(0);
    s16x8 af[4], bf[4];
#pragma unroll
    for (int m = 0; m < 4; m++)
      af[m] = *(const s16x8*)(&smA[cur][(wr * 64 + m * 16 + lr) * 32 + ((lg ^ rsw) * 8)]);
#pragma unroll
    for (int n = 0; n < 4; n++)
      bf[n] = *(const s16x8*)(&smB[cur][(wc * 64 + n * 16 + lr) * 32 + ((lg ^ rsw) * 8)]);
#pragma unroll
    for (int m = 0; m < 4; m++)
#pragma unroll
      for (int n = 0; n < 4; n++)
        acc[m][n] = __builtin_amdgcn_mfma_f32_16x16x32_bf16(af[m], bf[n], acc[m][n], 0, 0, 0);
    __builtin_amdgcn_s_barrier();
    cur = (cur == 2) ? 0 : cur + 1;
    sb  = (sb == 2) ? 0 : sb + 1;
  }
  float alpha = tanhf(gamma[0]) * 0.03125f;
#pragma unroll
  for (int n = 0; n < 4; n++) {
    int col = n0 + wc * 64 + n * 16 + lr;
#pragma unroll
    for (int m = 0; m < 4; m++) {
#pragma unroll
      for (int r = 0; r < 4; r++) {
        long row = m0 + wr * 64 + m * 16 + lg * 4 + r;
        C[(long)bz * Ln * Ln + row * Ln + col] = f2bf(acc[m][n][r] * alpha);
      }
    }
  }
}

// ---------------- fused gate + RoPE (inline trig, no tables) ----------------
// One block per (b,l): wave 0 computes gate = sigmoid(h.Wg2+bg2); then all 256
// threads rotate Q and K in place (thread t handles dims {2t,2t+1} x {+0,+512}).
__global__ __launch_bounds__(256)
void k_rope_fused(short* __restrict__ Q, short* __restrict__ Kx,
                  const short* __restrict__ Hfb,
                  const float* __restrict__ Wg2, const float* __restrict__ bg2) {
  __shared__ float smG;
  int bl = blockIdx.x;
  int l = bl & (Ln - 1);
  int t = threadIdx.x;
  if (t < 64) {
    s16x4 h4 = *(const s16x4*)(Hfb + (long)bl * HGn + t * 4);
    f32x4 w = *(const f32x4*)(Wg2 + t * 4);
    float s = bf2f(h4[0]) * w[0] + bf2f(h4[1]) * w[1] + bf2f(h4[2]) * w[2] + bf2f(h4[3]) * w[3];
#pragma unroll
    for (int m = 1; m < 64; m <<= 1) s += __shfl_xor(s, m);
    if (t == 0) smG = 1.0f / (1.0f + __expf(-(s + bg2[0])));
  }
  __syncthreads();
  float g = smG;
  int j = t * 2;
  float e0 = (float)j * (1.0f / 512.0f);
  float e1 = (float)(j + 1) * (1.0f / 512.0f);
  float invf0 = powf(1.6180339887498949f, -e0);
  float invf1 = powf(1.6180339887498949f, -e1);
  float invs0 = powf(1618.0f, -e0);
  float invs1 = powf(1618.0f, -e1);
  float lf = (float)l;
  float sf0, cf0, sf1, cf1, ss0, cs0, ss1, cs1;
  sincosf(lf * invf0, &sf0, &cf0);
  sincosf(lf * invf1, &sf1, &cf1);
  sincosf(lf * invs0, &ss0, &cs0);
  sincosf(lf * invs1, &ss1, &cs1);
  float c0 = g * cf0 + (1.f - g) * cs0;
  float c1 = g * cf1 + (1.f - g) * cs1;
  float s0 = g * sf0 + (1.f - g) * ss0;
  float s1 = g * sf1 + (1.f - g) * ss1;
  long base = (long)bl * Dn + j;
  {
    s16x2 xa = *(const s16x2*)(Q + base);
    s16x2 xb = *(const s16x2*)(Q + base + 512);
    float a0 = bf2f(xa[0]), a1 = bf2f(xa[1]), b0 = bf2f(xb[0]), b1 = bf2f(xb[1]);
    s16x2 o0, o1;
    o0[0] = f2bf(a0 * c0 - b0 * s0); o0[1] = f2bf(a1 * c1 - b1 * s1);
    o1[0] = f2bf(b0 * c0 + a0 * s0); o1[1] = f2bf(b1 * c1 + a1 * s1);
    *(s16x2*)(Q + base) = o0;
    *(s16x2*)(Q + base + 512) = o1;
  }
  {
    s16x2 xa = *(const s16x2*)(Kx + base);
    s16x2 xb = *(const s16x2*)(Kx + base + 512);
    float a0 = bf2f(xa[0]), a1 = bf2f(xa[1]), b0 = bf2f(xb[0]), b1 = bf2f(xb[1]);
    s16x2 o0, o1;
    o0[0] = f2bf(a0 * c0 - b0 * s0); o0[1] = f2bf(a1 * c1 - b1 * s1);
    o1[0] = f2bf(b0 * c0 + a0 * s0); o1[1] = f2bf(b1 * c1 + a1 * s1);
    *(s16x2*)(Kx + base) = o0;
    *(s16x2*)(Kx + base + 512) = o1;
  }
}

// ---------------- attention pass 1: uniform-work pairs (qb, 31-qb), XCD-grouped ----------------
__global__ __launch_bounds__(256)
void k_attn1(const short* __restrict__ Q, const short* __restrict__ Kx,
             const short* __restrict__ Vt, const short* __restrict__ Gb,
             float* __restrict__ outp, float* __restrict__ zinv) {
  int wg = blockIdx.x;              // 0..511
  int xcd = wg & 7, slot = wg >> 3; // slot 0..63
  int p = slot & 15, gh = slot >> 4;
  int g = gh * 8 + xcd;             // 0..31 (b,h) group
  int b = g >> 4, h = g & 15;

  int tid = threadIdx.x;
  int lane = tid & 63, w = tid >> 6;
  int lr = lane & 15, lg = lane >> 4;
  __shared__ short smK[2][64 * 64];
  __shared__ short smV[2][64 * 64];
  __shared__ short smP[4 * 16 * 64];
  short* pw = smP + w * 1024;

  int r0 = w * 16 + (lane >> 3);                 // staged row in tile (0..63)
  int scol = ((lane & 7) ^ (lane >> 3)) * 8;     // pre-swizzled source col (elems)
  const short* Kg = Kx + (long)(b * Ln) * Dn + h * 64;
  const short* Vg = Vt + (long)(b * NH + h) * 64 * Ln;
  int sw = (lr & 7) << 3;                        // read-side XOR (elems)

  for (int seg = 0; seg < 2; ++seg) {
    int qb = seg ? (31 - p) : p;
    int q0w = qb * 64 + w * 16;
    const short* qbp = Q + ((long)(b * Ln) + q0w + lr) * Dn + h * 64 + lg * 8;
    s16x8 qf0 = *(const s16x8*)(qbp);
    s16x8 qf1 = *(const s16x8*)(qbp + 32);
    f32x4 acc[4] = {};
    float az[4] = {0.f, 0.f, 0.f, 0.f};
    const short* gbase = Gb + ((long)b * Ln + q0w + lg * 4) * Ln + lr;

    int nt = qb + 1;
    auto stage = [&](int buf, int t) {
      long k0 = (long)t * 64;
      short* bK = &smK[buf][w * 1024];
      short* bV = &smV[buf][w * 1024];
      gl_lds16(Kg + (k0 + r0) * Dn + scol,           bK);
      gl_lds16(Kg + (k0 + r0 + 8) * Dn + scol,       bK + 512);
      gl_lds16(Vg + (long)r0 * Ln + k0 + scol,       bV);
      gl_lds16(Vg + (long)(r0 + 8) * Ln + k0 + scol, bV + 512);
    };

    float gcur[4][4], gnxt[4][4];
    stage(0, 0);
    {
      const short* g0 = gbase;
#pragma unroll
      for (int kk = 0; kk < 4; ++kk)
#pragma unroll
        for (int r = 0; r < 4; ++r) gcur[kk][r] = bf2f(g0[(long)r * Ln + kk * 16]);
    }
    int cur = 0;
    for (int t = 0; t < nt; ++t) {
      bool pre = (t + 1 < nt);
      if (pre) {
        const short* g0 = gbase + (t + 1) * 64;
#pragma unroll
        for (int kk = 0; kk < 4; ++kk)
#pragma unroll
          for (int r = 0; r < 4; ++r) gnxt[kk][r] = bf2f(g0[(long)r * Ln + kk * 16]);
        stage(cur ^ 1, t + 1);
      }
      __builtin_amdgcn_sched_barrier(0);
      if (pre) asm volatile("s_waitcnt vmcnt(20)" ::: "memory");
      else     asm volatile("s_waitcnt vmcnt(0)" ::: "memory");
      __builtin_amdgcn_s_barrier();
      __builtin_amdgcn_sched_barrier(0);
      int k0 = t * 64;
      const short* Kc = smK[cur];
      const short* Vc = smV[cur];
#pragma unroll
      for (int kk = 0; kk < 4; ++kk) {
        const short* kr = Kc + (kk * 16 + lr) * 64;
        s16x8 kf0 = *(const s16x8*)(kr + ((lg * 8) ^ sw));
        s16x8 kf1 = *(const s16x8*)(kr + ((32 + lg * 8) ^ sw));
        f32x4 S = {};
        S = __builtin_amdgcn_mfma_f32_16x16x32_bf16(qf0, kf0, S, 0, 0, 0);
        S = __builtin_amdgcn_mfma_f32_16x16x32_bf16(qf1, kf1, S, 0, 0, 0);
        int k = k0 + kk * 16 + lr;
#pragma unroll
        for (int r = 0; r < 4; r++) {
          int q = q0w + lg * 4 + r;
          float arg = (k <= q) ? (S[r] * 0.125f + gcur[kk][r]) : -80.0f;
          float pv = __expf(arg);
          az[r] += pv;
          int qq = lg * 4 + r;
          pw[qq * 64 + ((kk * 16 + lr) ^ ((qq & 7) << 3))] = f2bf(pv);
        }
      }
#pragma unroll
      for (int c = 0; c < 2; ++c) {
        s16x8 pf = *(const s16x8*)(pw + lr * 64 + ((c * 32 + lg * 8) ^ sw));
#pragma unroll
        for (int n = 0; n < 4; n++) {
          s16x8 vf = *(const s16x8*)(Vc + (n * 16 + lr) * 64 + ((c * 32 + lg * 8) ^ sw));
          acc[n] = __builtin_amdgcn_mfma_f32_16x16x32_bf16(pf, vf, acc[n], 0, 0, 0);
        }
      }
      __builtin_amdgcn_s_barrier();
      if (pre) {
#pragma unroll
        for (int kk = 0; kk < 4; ++kk)
#pragma unroll
          for (int r = 0; r < 4; ++r) gcur[kk][r] = gnxt[kk][r];
      }
      cur ^= 1;
    }
#pragma unroll
    for (int r = 0; r < 4; r++) {
      float z = az[r];
      z += __shfl_xor(z, 1); z += __shfl_xor(z, 2); z += __shfl_xor(z, 4); z += __shfl_xor(z, 8);
      az[r] = 1.0f / z;
    }
    if (lr == 0) {
#pragma unroll
      for (int r = 0; r < 4; r++)
        zinv[((long)(b * NH + h)) * Ln + q0w + lg * 4 + r] = az[r];
    }
#pragma unroll
    for (int n = 0; n < 4; n++) {
#pragma unroll
      for (int r = 0; r < 4; r++) {
        int q = q0w + lg * 4 + r;
        outp[((long)(b * Ln) + q) * Dn + h * 64 + n * 16 + lr] = acc[n][r] * az[r];
      }
    }
  }
}

// ---------------- attention pass 2: full 64x64 tile grid; upper tiles write zeros ----------------
__global__ __launch_bounds__(256)
void k_attn2(const short* __restrict__ Qm, const short* __restrict__ Kx,
             const short* __restrict__ Gb, const float* __restrict__ zinv, float* __restrict__ aw) {
  int b = blockIdx.y;
  int t = blockIdx.x;
  int qb = t >> 5, kb = t & 31;
  int q0 = qb * 64, k0 = kb * 64;
  int tid = threadIdx.x;
  if (kb > qb) {   // strict upper tile: zero-fill
    int row = tid >> 2, c4 = (tid & 3) << 4;
    float* basep = aw + ((long)b * Ln + q0 + row) * Ln + k0 + c4;
    f32x4 z = {};
    *(f32x4*)(basep) = z; *(f32x4*)(basep + 4) = z;
    *(f32x4*)(basep + 8) = z; *(f32x4*)(basep + 12) = z;
    return;
  }
  int lane = tid & 63, w = tid >> 6;
  int lr = lane & 15, lg = lane >> 4;
  int q0w = q0 + w * 16;
  bool diag = (qb == kb);
  __shared__ short smK[2][64 * 64];
  __shared__ short smQ[2][64 * 64];
  __shared__ float smZ[NH * 64];
  for (int i = tid; i < NH * 64; i += 256) {
    int h = i >> 6, qq = i & 63;
    smZ[i] = zinv[((long)(b * NH + h)) * Ln + q0 + qq];
  }
  __syncthreads();
  float gv[4][4];
#pragma unroll
  for (int n = 0; n < 4; n++) {
    int k = k0 + n * 16 + lr;
#pragma unroll
    for (int r = 0; r < 4; r++)
      gv[n][r] = bf2f(Gb[((long)b * Ln + q0w + lg * 4 + r) * Ln + k]);
  }
  int r0 = w * 16 + (lane >> 3);
  int scol = ((lane & 7) ^ (lane >> 3)) * 8;
  int sw = (lr & 7) << 3;
  auto stage = [&](int buf, int h) {
    short* bK = &smK[buf][w * 1024];
    short* bQ = &smQ[buf][w * 1024];
    const short* Kg = Kx + ((long)(b * Ln) + k0 + r0) * Dn + h * 64 + scol;
    gl_lds16(Kg, bK);
    gl_lds16(Kg + 8 * Dn, bK + 512);
    const short* Qg = Qm + ((long)(b * Ln) + q0 + r0) * Dn + h * 64 + scol;
    gl_lds16(Qg, bQ);
    gl_lds16(Qg + 8 * Dn, bQ + 512);
  };
  float wa[4][4] = {{0.f}};
  stage(0, 0);
  int cur = 0;
  for (int h = 0; h < NH; ++h) {
    bool pre = (h + 1 < NH);
    if (pre) stage(cur ^ 1, h + 1);
    __builtin_amdgcn_sched_barrier(0);
    if (pre) asm volatile("s_waitcnt vmcnt(4)" ::: "memory");
    else     asm volatile("s_waitcnt vmcnt(0)" ::: "memory");
    __builtin_amdgcn_s_barrier();
    __builtin_amdgcn_sched_barrier(0);
    const short* Kc = smK[cur];
    const short* Qc = smQ[cur];
    s16x8 qf0 = *(const s16x8*)(Qc + (w * 16 + lr) * 64 + ((lg * 8) ^ sw));
    s16x8 qf1 = *(const s16x8*)(Qc + (w * 16 + lr) * 64 + ((32 + lg * 8) ^ sw));
    float zq[4];
#pragma unroll
    for (int r = 0; r < 4; r++) zq[r] = smZ[h * 64 + w * 16 + lg * 4 + r];
#pragma unroll
    for (int n = 0; n < 4; n++) {
      const short* kr = Kc + (n * 16 + lr) * 64;
      s16x8 kf0 = *(const s16x8*)(kr + ((lg * 8) ^ sw));
      s16x8 kf1 = *(const s16x8*)(kr + ((32 + lg * 8) ^ sw));
      f32x4 S = {};
      S = __builtin_amdgcn_mfma_f32_16x16x32_bf16(qf0, kf0, S, 0, 0, 0);
      S = __builtin_amdgcn_mfma_f32_16x16x32_bf16(qf1, kf1, S, 0, 0, 0);
#pragma unroll
      for (int r = 0; r < 4; r++)
        wa[n][r] += __expf(S[r] * 0.125f + gv[n][r]) * zq[r];
    }
    __builtin_amdgcn_s_barrier();
    cur ^= 1;
  }
#pragma unroll
  for (int n = 0; n < 4; n++) {
    int k = k0 + n * 16 + lr;
#pragma unroll
    for (int r = 0; r < 4; r++) {
      int q = q0w + lg * 4 + r;
      float v = wa[n][r] * (1.0f / 16.0f);
      if (diag && k > q) v = 0.0f;
      aw[((long)b * Ln + q) * Ln + k] = v;
    }
  }
}

extern "C" void kernel_launch(void* const* d_in, const int* in_sizes, int n_in,
                              void* d_out, int out_size, void* d_ws, size_t ws_size,
                              hipStream_t stream) {
  const float* z    = (const float*)d_in[0];
  const float* ps   = (const float*)d_in[1];
  const float* Wq   = (const float*)d_in[2];
  const float* bq   = (const float*)d_in[3];
  const float* Wk   = (const float*)d_in[4];
  const float* bk   = (const float*)d_in[5];
  const float* Wv   = (const float*)d_in[6];
  const float* bv   = (const float*)d_in[7];
  const float* Wc   = (const float*)d_in[8];
  const float* gamma= (const float*)d_in[9];
  const float* Wg1  = (const float*)d_in[10];
  const float* bg1  = (const float*)d_in[11];
  const float* Wg2  = (const float*)d_in[12];
  const float* bg2  = (const float*)d_in[13];

  char* w = (char*)d_ws;
  auto alloc = [&](long bytes) { void* p = (void*)w; w += (bytes + 255) & ~255L; return p; };
  short* zb   = (short*)alloc(BLD * 2);                   // dead after mega GEMM
  short* pb   = (short*)alloc(BLD * 2);                   // dead after mega GEMM
  short* Wcat = (short*)alloc((long)(4 * Dn + HGn) * Dn * 2);
  short* Qp   = (short*)alloc(BLD * 2);
  short* Kp   = (short*)alloc(BLD * 2);
  short* Vtb  = (short*)alloc(BLD * 2);                   // V transposed: [b][h][d][L]
  short* Gk   = (short*)alloc(BLD * 2);
  short* Hfb  = (short*)alloc((long)Bn * Ln * HGn * 2);   // h in bf16
  float* zv   = (float*)alloc((long)Bn * NH * Ln * 4);
  short* Gb   = (short*)zb;   // 16.8MB bias slab aliases zb+pb (dead by then)

  float* outp = (float*)d_out;
  float* aw   = outp + BLD;

  // 1) fused casts (dst = zb|pb|Wcat contiguous)
  CastDesc cd;
  cd.src[0] = z;  cd.src[1] = ps; cd.src[2] = Wq; cd.src[3] = Wk;
  cd.src[4] = Wv; cd.src[5] = Wc; cd.src[6] = Wg1;
  long c0 = 0;
  cd.cum[0] = 0;
  cd.cum[1] = (c0 += BLD);
  cd.cum[2] = (c0 += BLD);
  cd.cum[3] = (c0 += (long)Dn * Dn);
  cd.cum[4] = (c0 += (long)Dn * Dn);
  cd.cum[5] = (c0 += (long)Dn * Dn);
  cd.cum[6] = (c0 += (long)Dn * Dn);
  cd.cum[7] = (c0 += (long)HGn * Dn);
  k_cast7<<<(int)(c0 / 1024), 256, 0, stream>>>(cd, zb);

  // 2) merged projections: Q,K,V(transposed),gk,h(GELU,bf16) — register-diet 128²
  k_gemm_mega<<<(4 * Dn + HGn) / 128 * ((Bn * Ln) / 128), 256, 0, stream>>>(
      zb, pb, Wcat, bq, bk, bv, bg1, Qp, Kp, Vtb, Gk, Hfb);

  // 3) gb (bf16, causal tiles only) -> aliased slab
  k_gemm_gb<<<dim3(16 * 17 / 2, Bn), 256, 0, stream>>>(Gk, Kp, gamma, Gb);

  // 4) fused gate + RoPE (inline trig; K raw already consumed by gb)
  k_rope_fused<<<Bn * Ln, 256, 0, stream>>>(Qp, Kp, Hfb, Wg2, bg2);

  // 5) attention
  k_attn1<<<512, 256, 0, stream>>>(Qp, Kp, Vtb, Gb, outp, zv);
  k_attn2<<<dim3(32 * 32, Bn), 256, 0, stream>>>(Qp, Kp, Gb, zv, aw);
}

// Round 14
// 230.173 us; speedup vs baseline: 1.6056x; 1.0136x over previous
//
#include <hip/hip_runtime.h>
#include <hip/hip_bf16.h>

// Problem constants (B=2, L=2048, D=1024, NH=16, HD=64, H_GATE=256)
constexpr int Bn  = 2;
constexpr int Ln  = 2048;
constexpr int Dn  = 1024;
constexpr int NH  = 16;
constexpr int HGn = 256;
constexpr long BLD = (long)Bn * Ln * Dn;   // 4194304

typedef float f32x4 __attribute__((ext_vector_type(4)));
typedef float f32x2 __attribute__((ext_vector_type(2)));
typedef short s16x8 __attribute__((ext_vector_type(8)));
typedef short s16x4 __attribute__((ext_vector_type(4)));
typedef short s16x2 __attribute__((ext_vector_type(2)));

#define DEVI static __device__ __forceinline__

DEVI float bf2f(short u) {
  union { float f; unsigned int i; } v; v.i = ((unsigned int)(unsigned short)u) << 16; return v.f;
}
DEVI short f2bf(float f) {
  union { float f; unsigned int i; } v; v.f = f;
  unsigned int r = v.i + 0x7FFFu + ((v.i >> 16) & 1u);
  return (short)(r >> 16);
}
DEVI void gl_lds16(const void* g, void* l) {
  __builtin_amdgcn_global_load_lds((const __attribute__((address_space(1))) unsigned int*)g,
                                   (__attribute__((address_space(3))) unsigned int*)l, 16, 0, 0);
}

// ---------------- fused 7-segment cast f32 -> bf16 (dst segments contiguous) ----------------
struct CastDesc { const float* src[7]; long cum[8]; };
__global__ void k_cast7(CastDesc d, short* __restrict__ dst) {
  long gi = ((long)blockIdx.x * 256 + threadIdx.x) * 4;
  int s = 0;
#pragma unroll
  for (int i = 1; i < 7; ++i) if (gi >= d.cum[i]) s = i;
  const float* sp = d.src[s] + (gi - d.cum[s]);
  f32x4 v = *(const f32x4*)sp;
  s16x4 o; o[0] = f2bf(v[0]); o[1] = f2bf(v[1]); o[2] = f2bf(v[2]); o[3] = f2bf(v[3]);
  *(s16x4*)(dst + gi) = o;
}

// ---------------- merged projection GEMM: 128x64 tile, acc[4][2], 4 waves/SIMD ----------------
// TLP experiment: 32 AGPR acc + ~64 VGPR -> 4 waves/SIMD -> 4 blocks/CU (Occ ~50%).
__global__ __launch_bounds__(256, 4)
void k_gemm_mega(const short* __restrict__ zb, const short* __restrict__ pb,
                 const short* __restrict__ Wcat,
                 const float* __restrict__ bq, const float* __restrict__ bk,
                 const float* __restrict__ bv, const float* __restrict__ bg1,
                 short* __restrict__ Qp, short* __restrict__ Kp,
                 short* __restrict__ Vtb, short* __restrict__ Gk,
                 short* __restrict__ Hfb) {
  // 2176 blocks = 8 XCD x (4 m-panels x 68 n-panels); n-outer, m-inner within XCD.
  int wgid = blockIdx.x;
  int xcd = wgid & 7, idx = wgid >> 3;      // idx 0..271
  int n0 = (idx >> 2) * 64;                 // 68 n-panels of 64
  int m0 = (xcd * 4 + (idx & 3)) * 128;     // 4 m-panels per XCD
  const short* Ap = (n0 < 3072) ? zb : pb;
  __shared__ short smA[2][128 * 32];        // 8 KB each
  __shared__ short smB[2][64 * 32];         // 4 KB each -> 24 KB total
  int tid = threadIdx.x;
  int lane = tid & 63, wid = tid >> 6;
  int wr = wid >> 1, wc = wid & 1;          // wave tile: 64 rows x 32 cols
  int lr = lane & 15, lg = lane >> 4;
  int r_in = lane >> 2;
  int slot = (lane & 3) * 8;
  int scol = ((lane & 3) ^ ((lane >> 3) & 3)) * 8;
  int rsw = (lr >> 1) & 3;
  f32x4 acc[4][2] = {};
  auto stage = [&](int buf, int k0) {
    int rowA = wid * 32 + r_in;
    gl_lds16(Ap   + (long)(m0 + rowA)      * Dn + k0 + scol, &smA[buf][rowA * 32 + slot]);
    gl_lds16(Ap   + (long)(m0 + rowA + 16) * Dn + k0 + scol, &smA[buf][(rowA + 16) * 32 + slot]);
    int rowB = wid * 16 + r_in;
    gl_lds16(Wcat + (long)(n0 + rowB)      * Dn + k0 + scol, &smB[buf][rowB * 32 + slot]);
  };
  stage(0, 0);
  int cur = 0;
  for (int k0 = 0; k0 < Dn; k0 += 32) {
    bool pre = (k0 + 32 < Dn);
    if (pre) stage(cur ^ 1, k0 + 32);
    __builtin_amdgcn_sched_barrier(0);
    if (pre) asm volatile("s_waitcnt vmcnt(3)" ::: "memory");
    else     asm volatile("s_waitcnt vmcnt(0)" ::: "memory");
    __builtin_amdgcn_s_barrier();
    __builtin_amdgcn_sched_barrier(0);
    const short* Ab = &smA[cur][(wr * 64 + lr) * 32 + ((lg ^ rsw) * 8)];
    const short* Bb = &smB[cur][(wc * 32 + lr) * 32 + ((lg ^ rsw) * 8)];
    s16x8 b0 = *(const s16x8*)(Bb);
    s16x8 b1 = *(const s16x8*)(Bb + 16 * 32);
#pragma unroll
    for (int m = 0; m < 4; m++) {
      s16x8 a = *(const s16x8*)(Ab + m * 16 * 32);
      acc[m][0] = __builtin_amdgcn_mfma_f32_16x16x32_bf16(a, b0, acc[m][0], 0, 0, 0);
      acc[m][1] = __builtin_amdgcn_mfma_f32_16x16x32_bf16(a, b1, acc[m][1], 0, 0, 0);
    }
    __builtin_amdgcn_s_barrier();
    cur ^= 1;
  }
  int slice = n0 >> 10;   // 0..4 (64-col panel never straddles a 1024 boundary)
#pragma unroll
  for (int n = 0; n < 2; n++) {
    int col = n0 + wc * 32 + n * 16 + lr;
    int c = col - (slice << 10);
    float bias = (slice == 0) ? bq[c] : (slice == 1) ? bk[c] : (slice == 2) ? bv[c]
               : (slice == 3) ? 0.0f : bg1[c];
#pragma unroll
    for (int m = 0; m < 4; m++) {
#pragma unroll
      for (int r = 0; r < 4; r++) {
        long row = m0 + wr * 64 + m * 16 + lg * 4 + r;
        float v = acc[m][n][r] + bias;
        if (slice == 4) {
          v = 0.5f * v * (1.0f + erff(v * 0.70710678118f));
          Hfb[row * HGn + c] = f2bf(v);
        } else if (slice == 2) {
          long off = (((row >> 11) * (long)NH + (c >> 6)) * 64 + (c & 63)) * Ln + (row & (Ln - 1));
          Vtb[off] = f2bf(v);
        } else {
          short* dst = (slice == 0) ? Qp : (slice == 1) ? Kp : Gk;
          dst[row * (long)Dn + c] = f2bf(v);
        }
      }
    }
  }
}

// ---------------- gb GEMM: Gb[b,q,k] = bf16( tanh(gamma)/32 * gk[q].K_raw[k] ), triangular grid ----------------
__global__ __launch_bounds__(256)
void k_gemm_gb(const short* __restrict__ A, const short* __restrict__ B,
               const float* __restrict__ gamma, short* __restrict__ C) {
  int bz = blockIdx.y;
  int t0 = blockIdx.x;
  int qb = (int)((sqrtf(8.0f * (float)t0 + 1.0f) - 1.0f) * 0.5f);
  while ((qb + 1) * (qb + 2) / 2 <= t0) ++qb;
  while (qb * (qb + 1) / 2 > t0) --qb;
  int kb = t0 - qb * (qb + 1) / 2;
  int m0 = qb * 128, n0 = kb * 128;
  const short* Ap = A + (long)bz * Ln * Dn;
  const short* Bp = B + (long)bz * Ln * Dn;
  __shared__ short smA[3][128 * 32];
  __shared__ short smB[3][128 * 32];
  int tid = threadIdx.x;
  int lane = tid & 63, wid = tid >> 6;
  int wr = wid >> 1, wc = wid & 1;
  int lr = lane & 15, lg = lane >> 4;
  int r_in = lane >> 2;
  int slot = (lane & 3) * 8;
  int scol = ((lane & 3) ^ ((lane >> 3) & 3)) * 8;
  int rsw = (lr >> 1) & 3;
  f32x4 acc[4][4] = {};
  auto stage = [&](int buf, int k0) {
    int rowA = wid * 32 + r_in;
    gl_lds16(Ap + (long)(m0 + rowA)      * Dn + k0 + scol, &smA[buf][rowA * 32 + slot]);
    gl_lds16(Ap + (long)(m0 + rowA + 16) * Dn + k0 + scol, &smA[buf][(rowA + 16) * 32 + slot]);
    gl_lds16(Bp + (long)(n0 + rowA)      * Dn + k0 + scol, &smB[buf][rowA * 32 + slot]);
    gl_lds16(Bp + (long)(n0 + rowA + 16) * Dn + k0 + scol, &smB[buf][(rowA + 16) * 32 + slot]);
  };
  stage(0, 0);
  stage(1, 32);
  int cur = 0, sb = 2;
  for (int t = 0; t < 32; ++t) {
    if (t + 2 < 32) stage(sb, (t + 2) * 32);
    __builtin_amdgcn_sched_barrier(0);
    int rem = 31 - t;
    if (rem >= 2)      asm volatile("s_waitcnt vmcnt(8)" ::: "memory");
    else if (rem == 1) asm volatile("s_waitcnt vmcnt(4)" ::: "memory");
    else               asm volatile("s_waitcnt vmcnt(0)" ::: "memory");
    __builtin_amdgcn_s_barrier();
    __builtin_amdgcn_sched_barrier(0);
    s16x8 af[4], bf[4];
#pragma unroll
    for (int m = 0; m < 4; m++)
      af[m] = *(const s16x8*)(&smA[cur][(wr * 64 + m * 16 + lr) * 32 + ((lg ^ rsw) * 8)]);
#pragma unroll
    for (int n = 0; n < 4; n++)
      bf[n] = *(const s16x8*)(&smB[cur][(wc * 64 + n * 16 + lr) * 32 + ((lg ^ rsw) * 8)]);
#pragma unroll
    for (int m = 0; m < 4; m++)
#pragma unroll
      for (int n = 0; n < 4; n++)
        acc[m][n] = __builtin_amdgcn_mfma_f32_16x16x32_bf16(af[m], bf[n], acc[m][n], 0, 0, 0);
    __builtin_amdgcn_s_barrier();
    cur = (cur == 2) ? 0 : cur + 1;
    sb  = (sb == 2) ? 0 : sb + 1;
  }
  float alpha = tanhf(gamma[0]) * 0.03125f;
#pragma unroll
  for (int n = 0; n < 4; n++) {
    int col = n0 + wc * 64 + n * 16 + lr;
#pragma unroll
    for (int m = 0; m < 4; m++) {
#pragma unroll
      for (int r = 0; r < 4; r++) {
        long row = m0 + wr * 64 + m * 16 + lg * 4 + r;
        C[(long)bz * Ln * Ln + row * Ln + col] = f2bf(acc[m][n][r] * alpha);
      }
    }
  }
}

// ---------------- fused gate + RoPE (inline trig, no tables) ----------------
__global__ __launch_bounds__(256)
void k_rope_fused(short* __restrict__ Q, short* __restrict__ Kx,
                  const short* __restrict__ Hfb,
                  const float* __restrict__ Wg2, const float* __restrict__ bg2) {
  __shared__ float smG;
  int bl = blockIdx.x;
  int l = bl & (Ln - 1);
  int t = threadIdx.x;
  if (t < 64) {
    s16x4 h4 = *(const s16x4*)(Hfb + (long)bl * HGn + t * 4);
    f32x4 w = *(const f32x4*)(Wg2 + t * 4);
    float s = bf2f(h4[0]) * w[0] + bf2f(h4[1]) * w[1] + bf2f(h4[2]) * w[2] + bf2f(h4[3]) * w[3];
#pragma unroll
    for (int m = 1; m < 64; m <<= 1) s += __shfl_xor(s, m);
    if (t == 0) smG = 1.0f / (1.0f + __expf(-(s + bg2[0])));
  }
  __syncthreads();
  float g = smG;
  int j = t * 2;
  float e0 = (float)j * (1.0f / 512.0f);
  float e1 = (float)(j + 1) * (1.0f / 512.0f);
  float invf0 = powf(1.6180339887498949f, -e0);
  float invf1 = powf(1.6180339887498949f, -e1);
  float invs0 = powf(1618.0f, -e0);
  float invs1 = powf(1618.0f, -e1);
  float lf = (float)l;
  float sf0, cf0, sf1, cf1, ss0, cs0, ss1, cs1;
  sincosf(lf * invf0, &sf0, &cf0);
  sincosf(lf * invf1, &sf1, &cf1);
  sincosf(lf * invs0, &ss0, &cs0);
  sincosf(lf * invs1, &ss1, &cs1);
  float c0 = g * cf0 + (1.f - g) * cs0;
  float c1 = g * cf1 + (1.f - g) * cs1;
  float s0 = g * sf0 + (1.f - g) * ss0;
  float s1 = g * sf1 + (1.f - g) * ss1;
  long base = (long)bl * Dn + j;
  {
    s16x2 xa = *(const s16x2*)(Q + base);
    s16x2 xb = *(const s16x2*)(Q + base + 512);
    float a0 = bf2f(xa[0]), a1 = bf2f(xa[1]), b0 = bf2f(xb[0]), b1 = bf2f(xb[1]);
    s16x2 o0, o1;
    o0[0] = f2bf(a0 * c0 - b0 * s0); o0[1] = f2bf(a1 * c1 - b1 * s1);
    o1[0] = f2bf(b0 * c0 + a0 * s0); o1[1] = f2bf(b1 * c1 + a1 * s1);
    *(s16x2*)(Q + base) = o0;
    *(s16x2*)(Q + base + 512) = o1;
  }
  {
    s16x2 xa = *(const s16x2*)(Kx + base);
    s16x2 xb = *(const s16x2*)(Kx + base + 512);
    float a0 = bf2f(xa[0]), a1 = bf2f(xa[1]), b0 = bf2f(xb[0]), b1 = bf2f(xb[1]);
    s16x2 o0, o1;
    o0[0] = f2bf(a0 * c0 - b0 * s0); o0[1] = f2bf(a1 * c1 - b1 * s1);
    o1[0] = f2bf(b0 * c0 + a0 * s0); o1[1] = f2bf(b1 * c1 + a1 * s1);
    *(s16x2*)(Kx + base) = o0;
    *(s16x2*)(Kx + base + 512) = o1;
  }
}

// ---------------- attention pass 1: uniform-work pairs (qb, 31-qb), XCD-grouped ----------------
__global__ __launch_bounds__(256)
void k_attn1(const short* __restrict__ Q, const short* __restrict__ Kx,
             const short* __restrict__ Vt, const short* __restrict__ Gb,
             float* __restrict__ outp, float* __restrict__ zinv) {
  int wg = blockIdx.x;              // 0..511
  int xcd = wg & 7, slot = wg >> 3; // slot 0..63
  int p = slot & 15, gh = slot >> 4;
  int g = gh * 8 + xcd;             // 0..31 (b,h) group
  int b = g >> 4, h = g & 15;

  int tid = threadIdx.x;
  int lane = tid & 63, w = tid >> 6;
  int lr = lane & 15, lg = lane >> 4;
  __shared__ short smK[2][64 * 64];
  __shared__ short smV[2][64 * 64];
  __shared__ short smP[4 * 16 * 64];
  short* pw = smP + w * 1024;

  int r0 = w * 16 + (lane >> 3);                 // staged row in tile (0..63)
  int scol = ((lane & 7) ^ (lane >> 3)) * 8;     // pre-swizzled source col (elems)
  const short* Kg = Kx + (long)(b * Ln) * Dn + h * 64;
  const short* Vg = Vt + (long)(b * NH + h) * 64 * Ln;
  int sw = (lr & 7) << 3;                        // read-side XOR (elems)

  for (int seg = 0; seg < 2; ++seg) {
    int qb = seg ? (31 - p) : p;
    int q0w = qb * 64 + w * 16;
    const short* qbp = Q + ((long)(b * Ln) + q0w + lr) * Dn + h * 64 + lg * 8;
    s16x8 qf0 = *(const s16x8*)(qbp);
    s16x8 qf1 = *(const s16x8*)(qbp + 32);
    f32x4 acc[4] = {};
    float az[4] = {0.f, 0.f, 0.f, 0.f};
    const short* gbase = Gb + ((long)b * Ln + q0w + lg * 4) * Ln + lr;

    int nt = qb + 1;
    auto stage = [&](int buf, int t) {
      long k0 = (long)t * 64;
      short* bK = &smK[buf][w * 1024];
      short* bV = &smV[buf][w * 1024];
      gl_lds16(Kg + (k0 + r0) * Dn + scol,           bK);
      gl_lds16(Kg + (k0 + r0 + 8) * Dn + scol,       bK + 512);
      gl_lds16(Vg + (long)r0 * Ln + k0 + scol,       bV);
      gl_lds16(Vg + (long)(r0 + 8) * Ln + k0 + scol, bV + 512);
    };

    float gcur[4][4], gnxt[4][4];
    stage(0, 0);
    {
      const short* g0 = gbase;
#pragma unroll
      for (int kk = 0; kk < 4; ++kk)
#pragma unroll
        for (int r = 0; r < 4; ++r) gcur[kk][r] = bf2f(g0[(long)r * Ln + kk * 16]);
    }
    int cur = 0;
    for (int t = 0; t < nt; ++t) {
      bool pre = (t + 1 < nt);
      if (pre) {
        const short* g0 = gbase + (t + 1) * 64;
#pragma unroll
        for (int kk = 0; kk < 4; ++kk)
#pragma unroll
          for (int r = 0; r < 4; ++r) gnxt[kk][r] = bf2f(g0[(long)r * Ln + kk * 16]);
        stage(cur ^ 1, t + 1);
      }
      __builtin_amdgcn_sched_barrier(0);
      if (pre) asm volatile("s_waitcnt vmcnt(20)" ::: "memory");
      else     asm volatile("s_waitcnt vmcnt(0)" ::: "memory");
      __builtin_amdgcn_s_barrier();
      __builtin_amdgcn_sched_barrier(0);
      int k0 = t * 64;
      const short* Kc = smK[cur];
      const short* Vc = smV[cur];
#pragma unroll
      for (int kk = 0; kk < 4; ++kk) {
        const short* kr = Kc + (kk * 16 + lr) * 64;
        s16x8 kf0 = *(const s16x8*)(kr + ((lg * 8) ^ sw));
        s16x8 kf1 = *(const s16x8*)(kr + ((32 + lg * 8) ^ sw));
        f32x4 S = {};
        S = __builtin_amdgcn_mfma_f32_16x16x32_bf16(qf0, kf0, S, 0, 0, 0);
        S = __builtin_amdgcn_mfma_f32_16x16x32_bf16(qf1, kf1, S, 0, 0, 0);
        int k = k0 + kk * 16 + lr;
#pragma unroll
        for (int r = 0; r < 4; r++) {
          int q = q0w + lg * 4 + r;
          float arg = (k <= q) ? (S[r] * 0.125f + gcur[kk][r]) : -80.0f;
          float pv = __expf(arg);
          az[r] += pv;
          int qq = lg * 4 + r;
          pw[qq * 64 + ((kk * 16 + lr) ^ ((qq & 7) << 3))] = f2bf(pv);
        }
      }
#pragma unroll
      for (int c = 0; c < 2; ++c) {
        s16x8 pf = *(const s16x8*)(pw + lr * 64 + ((c * 32 + lg * 8) ^ sw));
#pragma unroll
        for (int n = 0; n < 4; n++) {
          s16x8 vf = *(const s16x8*)(Vc + (n * 16 + lr) * 64 + ((c * 32 + lg * 8) ^ sw));
          acc[n] = __builtin_amdgcn_mfma_f32_16x16x32_bf16(pf, vf, acc[n], 0, 0, 0);
        }
      }
      __builtin_amdgcn_s_barrier();
      if (pre) {
#pragma unroll
        for (int kk = 0; kk < 4; ++kk)
#pragma unroll
          for (int r = 0; r < 4; ++r) gcur[kk][r] = gnxt[kk][r];
      }
      cur ^= 1;
    }
#pragma unroll
    for (int r = 0; r < 4; r++) {
      float z = az[r];
      z += __shfl_xor(z, 1); z += __shfl_xor(z, 2); z += __shfl_xor(z, 4); z += __shfl_xor(z, 8);
      az[r] = 1.0f / z;
    }
    if (lr == 0) {
#pragma unroll
      for (int r = 0; r < 4; r++)
        zinv[((long)(b * NH + h)) * Ln + q0w + lg * 4 + r] = az[r];
    }
#pragma unroll
    for (int n = 0; n < 4; n++) {
#pragma unroll
      for (int r = 0; r < 4; r++) {
        int q = q0w + lg * 4 + r;
        outp[((long)(b * Ln) + q) * Dn + h * 64 + n * 16 + lr] = acc[n][r] * az[r];
      }
    }
  }
}

// ---------------- attention pass 2: full 64x64 tile grid; upper tiles write zeros ----------------
__global__ __launch_bounds__(256)
void k_attn2(const short* __restrict__ Qm, const short* __restrict__ Kx,
             const short* __restrict__ Gb, const float* __restrict__ zinv, float* __restrict__ aw) {
  int b = blockIdx.y;
  int t = blockIdx.x;
  int qb = t >> 5, kb = t & 31;
  int q0 = qb * 64, k0 = kb * 64;
  int tid = threadIdx.x;
  if (kb > qb) {   // strict upper tile: zero-fill
    int row = tid >> 2, c4 = (tid & 3) << 4;
    float* basep = aw + ((long)b * Ln + q0 + row) * Ln + k0 + c4;
    f32x4 z = {};
    *(f32x4*)(basep) = z; *(f32x4*)(basep + 4) = z;
    *(f32x4*)(basep + 8) = z; *(f32x4*)(basep + 12) = z;
    return;
  }
  int lane = tid & 63, w = tid >> 6;
  int lr = lane & 15, lg = lane >> 4;
  int q0w = q0 + w * 16;
  bool diag = (qb == kb);
  __shared__ short smK[2][64 * 64];
  __shared__ short smQ[2][64 * 64];
  __shared__ float smZ[NH * 64];
  for (int i = tid; i < NH * 64; i += 256) {
    int h = i >> 6, qq = i & 63;
    smZ[i] = zinv[((long)(b * NH + h)) * Ln + q0 + qq];
  }
  __syncthreads();
  float gv[4][4];
#pragma unroll
  for (int n = 0; n < 4; n++) {
    int k = k0 + n * 16 + lr;
#pragma unroll
    for (int r = 0; r < 4; r++)
      gv[n][r] = bf2f(Gb[((long)b * Ln + q0w + lg * 4 + r) * Ln + k]);
  }
  int r0 = w * 16 + (lane >> 3);
  int scol = ((lane & 7) ^ (lane >> 3)) * 8;
  int sw = (lr & 7) << 3;
  auto stage = [&](int buf, int h) {
    short* bK = &smK[buf][w * 1024];
    short* bQ = &smQ[buf][w * 1024];
    const short* Kg = Kx + ((long)(b * Ln) + k0 + r0) * Dn + h * 64 + scol;
    gl_lds16(Kg, bK);
    gl_lds16(Kg + 8 * Dn, bK + 512);
    const short* Qg = Qm + ((long)(b * Ln) + q0 + r0) * Dn + h * 64 + scol;
    gl_lds16(Qg, bQ);
    gl_lds16(Qg + 8 * Dn, bQ + 512);
  };
  float wa[4][4] = {{0.f}};
  stage(0, 0);
  int cur = 0;
  for (int h = 0; h < NH; ++h) {
    bool pre = (h + 1 < NH);
    if (pre) stage(cur ^ 1, h + 1);
    __builtin_amdgcn_sched_barrier(0);
    if (pre) asm volatile("s_waitcnt vmcnt(4)" ::: "memory");
    else     asm volatile("s_waitcnt vmcnt(0)" ::: "memory");
    __builtin_amdgcn_s_barrier();
    __builtin_amdgcn_sched_barrier(0);
    const short* Kc = smK[cur];
    const short* Qc = smQ[cur];
    s16x8 qf0 = *(const s16x8*)(Qc + (w * 16 + lr) * 64 + ((lg * 8) ^ sw));
    s16x8 qf1 = *(const s16x8*)(Qc + (w * 16 + lr) * 64 + ((32 + lg * 8) ^ sw));
    float zq[4];
#pragma unroll
    for (int r = 0; r < 4; r++) zq[r] = smZ[h * 64 + w * 16 + lg * 4 + r];
#pragma unroll
    for (int n = 0; n < 4; n++) {
      const short* kr = Kc + (n * 16 + lr) * 64;
      s16x8 kf0 = *(const s16x8*)(kr + ((lg * 8) ^ sw));
      s16x8 kf1 = *(const s16x8*)(kr + ((32 + lg * 8) ^ sw));
      f32x4 S = {};
      S = __builtin_amdgcn_mfma_f32_16x16x32_bf16(qf0, kf0, S, 0, 0, 0);
      S = __builtin_amdgcn_mfma_f32_16x16x32_bf16(qf1, kf1, S, 0, 0, 0);
#pragma unroll
      for (int r = 0; r < 4; r++)
        wa[n][r] += __expf(S[r] * 0.125f + gv[n][r]) * zq[r];
    }
    __builtin_amdgcn_s_barrier();
    cur ^= 1;
  }
#pragma unroll
  for (int n = 0; n < 4; n++) {
    int k = k0 + n * 16 + lr;
#pragma unroll
    for (int r = 0; r < 4; r++) {
      int q = q0w + lg * 4 + r;
      float v = wa[n][r] * (1.0f / 16.0f);
      if (diag && k > q) v = 0.0f;
      aw[((long)b * Ln + q) * Ln + k] = v;
    }
  }
}

extern "C" void kernel_launch(void* const* d_in, const int* in_sizes, int n_in,
                              void* d_out, int out_size, void* d_ws, size_t ws_size,
                              hipStream_t stream) {
  const float* z    = (const float*)d_in[0];
  const float* ps   = (const float*)d_in[1];
  const float* Wq   = (const float*)d_in[2];
  const float* bq   = (const float*)d_in[3];
  const float* Wk   = (const float*)d_in[4];
  const float* bk   = (const float*)d_in[5];
  const float* Wv   = (const float*)d_in[6];
  const float* bv   = (const float*)d_in[7];
  const float* Wc   = (const float*)d_in[8];
  const float* gamma= (const float*)d_in[9];
  const float* Wg1  = (const float*)d_in[10];
  const float* bg1  = (const float*)d_in[11];
  const float* Wg2  = (const float*)d_in[12];
  const float* bg2  = (const float*)d_in[13];

  char* w = (char*)d_ws;
  auto alloc = [&](long bytes) { void* p = (void*)w; w += (bytes + 255) & ~255L; return p; };
  short* zb   = (short*)alloc(BLD * 2);                   // dead after mega GEMM
  short* pb   = (short*)alloc(BLD * 2);                   // dead after mega GEMM
  short* Wcat = (short*)alloc((long)(4 * Dn + HGn) * Dn * 2);
  short* Qp   = (short*)alloc(BLD * 2);
  short* Kp   = (short*)alloc(BLD * 2);
  short* Vtb  = (short*)alloc(BLD * 2);                   // V transposed: [b][h][d][L]
  short* Gk   = (short*)alloc(BLD * 2);
  short* Hfb  = (short*)alloc((long)Bn * Ln * HGn * 2);   // h in bf16
  float* zv   = (float*)alloc((long)Bn * NH * Ln * 4);
  short* Gb   = (short*)zb;   // 16.8MB bias slab aliases zb+pb (dead by then)

  float* outp = (float*)d_out;
  float* aw   = outp + BLD;

  // 1) fused casts (dst = zb|pb|Wcat contiguous)
  CastDesc cd;
  cd.src[0] = z;  cd.src[1] = ps; cd.src[2] = Wq; cd.src[3] = Wk;
  cd.src[4] = Wv; cd.src[5] = Wc; cd.src[6] = Wg1;
  long c0 = 0;
  cd.cum[0] = 0;
  cd.cum[1] = (c0 += BLD);
  cd.cum[2] = (c0 += BLD);
  cd.cum[3] = (c0 += (long)Dn * Dn);
  cd.cum[4] = (c0 += (long)Dn * Dn);
  cd.cum[5] = (c0 += (long)Dn * Dn);
  cd.cum[6] = (c0 += (long)Dn * Dn);
  cd.cum[7] = (c0 += (long)HGn * Dn);
  k_cast7<<<(int)(c0 / 1024), 256, 0, stream>>>(cd, zb);

  // 2) merged projections — 128x64 tile, 4 waves/SIMD TLP experiment
  k_gemm_mega<<<2176, 256, 0, stream>>>(zb, pb, Wcat, bq, bk, bv, bg1, Qp, Kp, Vtb, Gk, Hfb);

  // 3) gb (bf16, causal tiles only) -> aliased slab
  k_gemm_gb<<<dim3(16 * 17 / 2, Bn), 256, 0, stream>>>(Gk, Kp, gamma, Gb);

  // 4) fused gate + RoPE (inline trig; K raw already consumed by gb)
  k_rope_fused<<<Bn * Ln, 256, 0, stream>>>(Qp, Kp, Hfb, Wg2, bg2);

  // 5) attention
  k_attn1<<<512, 256, 0, stream>>>(Qp, Kp, Vtb, Gb, outp, zv);
  k_attn2<<<dim3(32 * 32, Bn), 256, 0, stream>>>(Qp, Kp, Gb, zv, aw);
}

// Round 15
// 226.557 us; speedup vs baseline: 1.6313x; 1.0160x over previous
//
#include <hip/hip_runtime.h>
#include <hip/hip_bf16.h>

// Problem constants (B=2, L=2048, D=1024, NH=16, HD=64, H_GATE=256)
constexpr int Bn  = 2;
constexpr int Ln  = 2048;
constexpr int Dn  = 1024;
constexpr int NH  = 16;
constexpr int HGn = 256;
constexpr long BLD = (long)Bn * Ln * Dn;   // 4194304

typedef float f32x4 __attribute__((ext_vector_type(4)));
typedef float f32x2 __attribute__((ext_vector_type(2)));
typedef short s16x8 __attribute__((ext_vector_type(8)));
typedef short s16x4 __attribute__((ext_vector_type(4)));
typedef short s16x2 __attribute__((ext_vector_type(2)));

#define DEVI static __device__ __forceinline__

DEVI float bf2f(short u) {
  union { float f; unsigned int i; } v; v.i = ((unsigned int)(unsigned short)u) << 16; return v.f;
}
DEVI short f2bf(float f) {
  union { float f; unsigned int i; } v; v.f = f;
  unsigned int r = v.i + 0x7FFFu + ((v.i >> 16) & 1u);
  return (short)(r >> 16);
}
DEVI void gl_lds16(const void* g, void* l) {
  __builtin_amdgcn_global_load_lds((const __attribute__((address_space(1))) unsigned int*)g,
                                   (__attribute__((address_space(3))) unsigned int*)l, 16, 0, 0);
}

// ---------------- fused 7-segment cast f32 -> bf16 (dst segments contiguous) ----------------
struct CastDesc { const float* src[7]; long cum[8]; };
__global__ void k_cast7(CastDesc d, short* __restrict__ dst) {
  long gi = ((long)blockIdx.x * 256 + threadIdx.x) * 4;
  int s = 0;
#pragma unroll
  for (int i = 1; i < 7; ++i) if (gi >= d.cum[i]) s = i;
  const float* sp = d.src[s] + (gi - d.cum[s]);
  f32x4 v = *(const f32x4*)sp;
  s16x4 o; o[0] = f2bf(v[0]); o[1] = f2bf(v[1]); o[2] = f2bf(v[2]); o[3] = f2bf(v[3]);
  *(s16x4*)(dst + gi) = o;
}

// ---------------- merged projection GEMM: 128x64 tile, acc[4][2], 6 waves/SIMD ----------------
__global__ __launch_bounds__(256, 6)
void k_gemm_mega(const short* __restrict__ zb, const short* __restrict__ pb,
                 const short* __restrict__ Wcat,
                 const float* __restrict__ bq, const float* __restrict__ bk,
                 const float* __restrict__ bv, const float* __restrict__ bg1,
                 short* __restrict__ Qp, short* __restrict__ Kp,
                 short* __restrict__ Vtb, short* __restrict__ Gk,
                 short* __restrict__ Hfb) {
  // 2176 blocks = 8 XCD x (4 m-panels x 68 n-panels); n-outer, m-inner within XCD.
  int wgid = blockIdx.x;
  int xcd = wgid & 7, idx = wgid >> 3;      // idx 0..271
  int n0 = (idx >> 2) * 64;                 // 68 n-panels of 64
  int m0 = (xcd * 4 + (idx & 3)) * 128;     // 4 m-panels per XCD
  const short* Ap = (n0 < 3072) ? zb : pb;
  __shared__ short smA[2][128 * 32];
  __shared__ short smB[2][64 * 32];
  int tid = threadIdx.x;
  int lane = tid & 63, wid = tid >> 6;
  int wr = wid >> 1, wc = wid & 1;          // wave tile: 64 rows x 32 cols
  int lr = lane & 15, lg = lane >> 4;
  int r_in = lane >> 2;
  int slot = (lane & 3) * 8;
  int scol = ((lane & 3) ^ ((lane >> 3) & 3)) * 8;
  int rsw = (lr >> 1) & 3;
  f32x4 acc[4][2] = {};
  auto stage = [&](int buf, int k0) {
    int rowA = wid * 32 + r_in;
    gl_lds16(Ap   + (long)(m0 + rowA)      * Dn + k0 + scol, &smA[buf][rowA * 32 + slot]);
    gl_lds16(Ap   + (long)(m0 + rowA + 16) * Dn + k0 + scol, &smA[buf][(rowA + 16) * 32 + slot]);
    int rowB = wid * 16 + r_in;
    gl_lds16(Wcat + (long)(n0 + rowB)      * Dn + k0 + scol, &smB[buf][rowB * 32 + slot]);
  };
  stage(0, 0);
  int cur = 0;
  for (int k0 = 0; k0 < Dn; k0 += 32) {
    bool pre = (k0 + 32 < Dn);
    if (pre) stage(cur ^ 1, k0 + 32);
    __builtin_amdgcn_sched_barrier(0);
    if (pre) asm volatile("s_waitcnt vmcnt(3)" ::: "memory");
    else     asm volatile("s_waitcnt vmcnt(0)" ::: "memory");
    __builtin_amdgcn_s_barrier();
    __builtin_amdgcn_sched_barrier(0);
    const short* Ab = &smA[cur][(wr * 64 + lr) * 32 + ((lg ^ rsw) * 8)];
    const short* Bb = &smB[cur][(wc * 32 + lr) * 32 + ((lg ^ rsw) * 8)];
    s16x8 b0 = *(const s16x8*)(Bb);
    s16x8 b1 = *(const s16x8*)(Bb + 16 * 32);
#pragma unroll
    for (int m = 0; m < 4; m++) {
      s16x8 a = *(const s16x8*)(Ab + m * 16 * 32);
      acc[m][0] = __builtin_amdgcn_mfma_f32_16x16x32_bf16(a, b0, acc[m][0], 0, 0, 0);
      acc[m][1] = __builtin_amdgcn_mfma_f32_16x16x32_bf16(a, b1, acc[m][1], 0, 0, 0);
    }
    __builtin_amdgcn_s_barrier();
    cur ^= 1;
  }
  int slice = n0 >> 10;   // 0..4 (64-col panel never straddles a 1024 boundary)
#pragma unroll
  for (int n = 0; n < 2; n++) {
    int col = n0 + wc * 32 + n * 16 + lr;
    int c = col - (slice << 10);
    float bias = (slice == 0) ? bq[c] : (slice == 1) ? bk[c] : (slice == 2) ? bv[c]
               : (slice == 3) ? 0.0f : bg1[c];
#pragma unroll
    for (int m = 0; m < 4; m++) {
#pragma unroll
      for (int r = 0; r < 4; r++) {
        long row = m0 + wr * 64 + m * 16 + lg * 4 + r;
        float v = acc[m][n][r] + bias;
        if (slice == 4) {
          v = 0.5f * v * (1.0f + erff(v * 0.70710678118f));
          Hfb[row * HGn + c] = f2bf(v);
        } else if (slice == 2) {
          long off = (((row >> 11) * (long)NH + (c >> 6)) * 64 + (c & 63)) * Ln + (row & (Ln - 1));
          Vtb[off] = f2bf(v);
        } else {
          short* dst = (slice == 0) ? Qp : (slice == 1) ? Kp : Gk;
          dst[row * (long)Dn + c] = f2bf(v);
        }
      }
    }
  }
}

// ---------------- gb GEMM (diet): 128x64 tiles over causal panels, acc[4][2] ----------------
// Row-panels of 128 (qp=0..15), col-panels of 64 (kp=0..2qp+1). 272 tiles/batch.
__global__ __launch_bounds__(256, 6)
void k_gemm_gbd(const short* __restrict__ A, const short* __restrict__ B,
                const float* __restrict__ gamma, short* __restrict__ C) {
  int bz = blockIdx.y;
  int t0 = blockIdx.x;                  // 0..271
  int qp = (int)((sqrtf(4.0f * (float)t0 + 1.0f) - 1.0f) * 0.5f);
  while ((qp + 1) * (qp + 2) <= t0) ++qp;
  while (qp * (qp + 1) > t0) --qp;
  int kp = t0 - qp * (qp + 1);          // 0..2qp+1
  int m0 = qp * 128, n0 = kp * 64;
  const short* Ap = A + (long)bz * Ln * Dn;
  const short* Bp = B + (long)bz * Ln * Dn;
  __shared__ short smA[2][128 * 32];
  __shared__ short smB[2][64 * 32];
  int tid = threadIdx.x;
  int lane = tid & 63, wid = tid >> 6;
  int wr = wid >> 1, wc = wid & 1;
  int lr = lane & 15, lg = lane >> 4;
  int r_in = lane >> 2;
  int slot = (lane & 3) * 8;
  int scol = ((lane & 3) ^ ((lane >> 3) & 3)) * 8;
  int rsw = (lr >> 1) & 3;
  f32x4 acc[4][2] = {};
  auto stage = [&](int buf, int k0) {
    int rowA = wid * 32 + r_in;
    gl_lds16(Ap + (long)(m0 + rowA)      * Dn + k0 + scol, &smA[buf][rowA * 32 + slot]);
    gl_lds16(Ap + (long)(m0 + rowA + 16) * Dn + k0 + scol, &smA[buf][(rowA + 16) * 32 + slot]);
    int rowB = wid * 16 + r_in;
    gl_lds16(Bp + (long)(n0 + rowB)      * Dn + k0 + scol, &smB[buf][rowB * 32 + slot]);
  };
  stage(0, 0);
  int cur = 0;
  for (int k0 = 0; k0 < Dn; k0 += 32) {
    bool pre = (k0 + 32 < Dn);
    if (pre) stage(cur ^ 1, k0 + 32);
    __builtin_amdgcn_sched_barrier(0);
    if (pre) asm volatile("s_waitcnt vmcnt(3)" ::: "memory");
    else     asm volatile("s_waitcnt vmcnt(0)" ::: "memory");
    __builtin_amdgcn_s_barrier();
    __builtin_amdgcn_sched_barrier(0);
    const short* Ab = &smA[cur][(wr * 64 + lr) * 32 + ((lg ^ rsw) * 8)];
    const short* Bb = &smB[cur][(wc * 32 + lr) * 32 + ((lg ^ rsw) * 8)];
    s16x8 b0 = *(const s16x8*)(Bb);
    s16x8 b1 = *(const s16x8*)(Bb + 16 * 32);
#pragma unroll
    for (int m = 0; m < 4; m++) {
      s16x8 a = *(const s16x8*)(Ab + m * 16 * 32);
      acc[m][0] = __builtin_amdgcn_mfma_f32_16x16x32_bf16(a, b0, acc[m][0], 0, 0, 0);
      acc[m][1] = __builtin_amdgcn_mfma_f32_16x16x32_bf16(a, b1, acc[m][1], 0, 0, 0);
    }
    __builtin_amdgcn_s_barrier();
    cur ^= 1;
  }
  float alpha = tanhf(gamma[0]) * 0.03125f;
#pragma unroll
  for (int n = 0; n < 2; n++) {
    int col = n0 + wc * 32 + n * 16 + lr;
#pragma unroll
    for (int m = 0; m < 4; m++) {
#pragma unroll
      for (int r = 0; r < 4; r++) {
        long row = m0 + wr * 64 + m * 16 + lg * 4 + r;
        C[(long)bz * Ln * Ln + row * Ln + col] = f2bf(acc[m][n][r] * alpha);
      }
    }
  }
}

// ---------------- fused gate + RoPE (inline trig, no tables) ----------------
__global__ __launch_bounds__(256)
void k_rope_fused(short* __restrict__ Q, short* __restrict__ Kx,
                  const short* __restrict__ Hfb,
                  const float* __restrict__ Wg2, const float* __restrict__ bg2) {
  __shared__ float smG;
  int bl = blockIdx.x;
  int l = bl & (Ln - 1);
  int t = threadIdx.x;
  if (t < 64) {
    s16x4 h4 = *(const s16x4*)(Hfb + (long)bl * HGn + t * 4);
    f32x4 w = *(const f32x4*)(Wg2 + t * 4);
    float s = bf2f(h4[0]) * w[0] + bf2f(h4[1]) * w[1] + bf2f(h4[2]) * w[2] + bf2f(h4[3]) * w[3];
#pragma unroll
    for (int m = 1; m < 64; m <<= 1) s += __shfl_xor(s, m);
    if (t == 0) smG = 1.0f / (1.0f + __expf(-(s + bg2[0])));
  }
  __syncthreads();
  float g = smG;
  int j = t * 2;
  float e0 = (float)j * (1.0f / 512.0f);
  float e1 = (float)(j + 1) * (1.0f / 512.0f);
  float invf0 = powf(1.6180339887498949f, -e0);
  float invf1 = powf(1.6180339887498949f, -e1);
  float invs0 = powf(1618.0f, -e0);
  float invs1 = powf(1618.0f, -e1);
  float lf = (float)l;
  float sf0, cf0, sf1, cf1, ss0, cs0, ss1, cs1;
  sincosf(lf * invf0, &sf0, &cf0);
  sincosf(lf * invf1, &sf1, &cf1);
  sincosf(lf * invs0, &ss0, &cs0);
  sincosf(lf * invs1, &ss1, &cs1);
  float c0 = g * cf0 + (1.f - g) * cs0;
  float c1 = g * cf1 + (1.f - g) * cs1;
  float s0 = g * sf0 + (1.f - g) * ss0;
  float s1 = g * sf1 + (1.f - g) * ss1;
  long base = (long)bl * Dn + j;
  {
    s16x2 xa = *(const s16x2*)(Q + base);
    s16x2 xb = *(const s16x2*)(Q + base + 512);
    float a0 = bf2f(xa[0]), a1 = bf2f(xa[1]), b0 = bf2f(xb[0]), b1 = bf2f(xb[1]);
    s16x2 o0, o1;
    o0[0] = f2bf(a0 * c0 - b0 * s0); o0[1] = f2bf(a1 * c1 - b1 * s1);
    o1[0] = f2bf(b0 * c0 + a0 * s0); o1[1] = f2bf(b1 * c1 + a1 * s1);
    *(s16x2*)(Q + base) = o0;
    *(s16x2*)(Q + base + 512) = o1;
  }
  {
    s16x2 xa = *(const s16x2*)(Kx + base);
    s16x2 xb = *(const s16x2*)(Kx + base + 512);
    float a0 = bf2f(xa[0]), a1 = bf2f(xa[1]), b0 = bf2f(xb[0]), b1 = bf2f(xb[1]);
    s16x2 o0, o1;
    o0[0] = f2bf(a0 * c0 - b0 * s0); o0[1] = f2bf(a1 * c1 - b1 * s1);
    o1[0] = f2bf(b0 * c0 + a0 * s0); o1[1] = f2bf(b1 * c1 + a1 * s1);
    *(s16x2*)(Kx + base) = o0;
    *(s16x2*)(Kx + base + 512) = o1;
  }
}

// ---------------- attention pass 1: uniform-work pairs (qb, 31-qb), XCD-grouped ----------------
__global__ __launch_bounds__(256)
void k_attn1(const short* __restrict__ Q, const short* __restrict__ Kx,
             const short* __restrict__ Vt, const short* __restrict__ Gb,
             float* __restrict__ outp, float* __restrict__ zinv) {
  int wg = blockIdx.x;              // 0..511
  int xcd = wg & 7, slot = wg >> 3; // slot 0..63
  int p = slot & 15, gh = slot >> 4;
  int g = gh * 8 + xcd;             // 0..31 (b,h) group
  int b = g >> 4, h = g & 15;

  int tid = threadIdx.x;
  int lane = tid & 63, w = tid >> 6;
  int lr = lane & 15, lg = lane >> 4;
  __shared__ short smK[2][64 * 64];
  __shared__ short smV[2][64 * 64];
  __shared__ short smP[4 * 16 * 64];
  short* pw = smP + w * 1024;

  int r0 = w * 16 + (lane >> 3);                 // staged row in tile (0..63)
  int scol = ((lane & 7) ^ (lane >> 3)) * 8;     // pre-swizzled source col (elems)
  const short* Kg = Kx + (long)(b * Ln) * Dn + h * 64;
  const short* Vg = Vt + (long)(b * NH + h) * 64 * Ln;
  int sw = (lr & 7) << 3;                        // read-side XOR (elems)

  for (int seg = 0; seg < 2; ++seg) {
    int qb = seg ? (31 - p) : p;
    int q0w = qb * 64 + w * 16;
    const short* qbp = Q + ((long)(b * Ln) + q0w + lr) * Dn + h * 64 + lg * 8;
    s16x8 qf0 = *(const s16x8*)(qbp);
    s16x8 qf1 = *(const s16x8*)(qbp + 32);
    f32x4 acc[4] = {};
    float az[4] = {0.f, 0.f, 0.f, 0.f};
    const short* gbase = Gb + ((long)b * Ln + q0w + lg * 4) * Ln + lr;

    int nt = qb + 1;
    auto stage = [&](int buf, int t) {
      long k0 = (long)t * 64;
      short* bK = &smK[buf][w * 1024];
      short* bV = &smV[buf][w * 1024];
      gl_lds16(Kg + (k0 + r0) * Dn + scol,           bK);
      gl_lds16(Kg + (k0 + r0 + 8) * Dn + scol,       bK + 512);
      gl_lds16(Vg + (long)r0 * Ln + k0 + scol,       bV);
      gl_lds16(Vg + (long)(r0 + 8) * Ln + k0 + scol, bV + 512);
    };

    float gcur[4][4], gnxt[4][4];
    stage(0, 0);
    {
      const short* g0 = gbase;
#pragma unroll
      for (int kk = 0; kk < 4; ++kk)
#pragma unroll
        for (int r = 0; r < 4; ++r) gcur[kk][r] = bf2f(g0[(long)r * Ln + kk * 16]);
    }
    int cur = 0;
    for (int t = 0; t < nt; ++t) {
      bool pre = (t + 1 < nt);
      if (pre) {
        const short* g0 = gbase + (t + 1) * 64;
#pragma unroll
        for (int kk = 0; kk < 4; ++kk)
#pragma unroll
          for (int r = 0; r < 4; ++r) gnxt[kk][r] = bf2f(g0[(long)r * Ln + kk * 16]);
        stage(cur ^ 1, t + 1);
      }
      __builtin_amdgcn_sched_barrier(0);
      if (pre) asm volatile("s_waitcnt vmcnt(20)" ::: "memory");
      else     asm volatile("s_waitcnt vmcnt(0)" ::: "memory");
      __builtin_amdgcn_s_barrier();
      __builtin_amdgcn_sched_barrier(0);
      int k0 = t * 64;
      const short* Kc = smK[cur];
      const short* Vc = smV[cur];
#pragma unroll
      for (int kk = 0; kk < 4; ++kk) {
        const short* kr = Kc + (kk * 16 + lr) * 64;
        s16x8 kf0 = *(const s16x8*)(kr + ((lg * 8) ^ sw));
        s16x8 kf1 = *(const s16x8*)(kr + ((32 + lg * 8) ^ sw));
        f32x4 S = {};
        S = __builtin_amdgcn_mfma_f32_16x16x32_bf16(qf0, kf0, S, 0, 0, 0);
        S = __builtin_amdgcn_mfma_f32_16x16x32_bf16(qf1, kf1, S, 0, 0, 0);
        int k = k0 + kk * 16 + lr;
#pragma unroll
        for (int r = 0; r < 4; r++) {
          int q = q0w + lg * 4 + r;
          float arg = (k <= q) ? (S[r] * 0.125f + gcur[kk][r]) : -80.0f;
          float pv = __expf(arg);
          az[r] += pv;
          int qq = lg * 4 + r;
          pw[qq * 64 + ((kk * 16 + lr) ^ ((qq & 7) << 3))] = f2bf(pv);
        }
      }
#pragma unroll
      for (int c = 0; c < 2; ++c) {
        s16x8 pf = *(const s16x8*)(pw + lr * 64 + ((c * 32 + lg * 8) ^ sw));
#pragma unroll
        for (int n = 0; n < 4; n++) {
          s16x8 vf = *(const s16x8*)(Vc + (n * 16 + lr) * 64 + ((c * 32 + lg * 8) ^ sw));
          acc[n] = __builtin_amdgcn_mfma_f32_16x16x32_bf16(pf, vf, acc[n], 0, 0, 0);
        }
      }
      __builtin_amdgcn_s_barrier();
      if (pre) {
#pragma unroll
        for (int kk = 0; kk < 4; ++kk)
#pragma unroll
          for (int r = 0; r < 4; ++r) gcur[kk][r] = gnxt[kk][r];
      }
      cur ^= 1;
    }
#pragma unroll
    for (int r = 0; r < 4; r++) {
      float z = az[r];
      z += __shfl_xor(z, 1); z += __shfl_xor(z, 2); z += __shfl_xor(z, 4); z += __shfl_xor(z, 8);
      az[r] = 1.0f / z;
    }
    if (lr == 0) {
#pragma unroll
      for (int r = 0; r < 4; r++)
        zinv[((long)(b * NH + h)) * Ln + q0w + lg * 4 + r] = az[r];
    }
#pragma unroll
    for (int n = 0; n < 4; n++) {
#pragma unroll
      for (int r = 0; r < 4; r++) {
        int q = q0w + lg * 4 + r;
        outp[((long)(b * Ln) + q) * Dn + h * 64 + n * 16 + lr] = acc[n][r] * az[r];
      }
    }
  }
}

// ---------------- attention pass 2: full 64x64 tile grid; upper tiles write zeros ----------------
__global__ __launch_bounds__(256)
void k_attn2(const short* __restrict__ Qm, const short* __restrict__ Kx,
             const short* __restrict__ Gb, const float* __restrict__ zinv, float* __restrict__ aw) {
  int b = blockIdx.y;
  int t = blockIdx.x;
  int qb = t >> 5, kb = t & 31;
  int q0 = qb * 64, k0 = kb * 64;
  int tid = threadIdx.x;
  if (kb > qb) {   // strict upper tile: zero-fill
    int row = tid >> 2, c4 = (tid & 3) << 4;
    float* basep = aw + ((long)b * Ln + q0 + row) * Ln + k0 + c4;
    f32x4 z = {};
    *(f32x4*)(basep) = z; *(f32x4*)(basep + 4) = z;
    *(f32x4*)(basep + 8) = z; *(f32x4*)(basep + 12) = z;
    return;
  }
  int lane = tid & 63, w = tid >> 6;
  int lr = lane & 15, lg = lane >> 4;
  int q0w = q0 + w * 16;
  bool diag = (qb == kb);
  __shared__ short smK[2][64 * 64];
  __shared__ short smQ[2][64 * 64];
  __shared__ float smZ[NH * 64];
  for (int i = tid; i < NH * 64; i += 256) {
    int h = i >> 6, qq = i & 63;
    smZ[i] = zinv[((long)(b * NH + h)) * Ln + q0 + qq];
  }
  __syncthreads();
  float gv[4][4];
#pragma unroll
  for (int n = 0; n < 4; n++) {
    int k = k0 + n * 16 + lr;
#pragma unroll
    for (int r = 0; r < 4; r++)
      gv[n][r] = bf2f(Gb[((long)b * Ln + q0w + lg * 4 + r) * Ln + k]);
  }
  int r0 = w * 16 + (lane >> 3);
  int scol = ((lane & 7) ^ (lane >> 3)) * 8;
  int sw = (lr & 7) << 3;
  auto stage = [&](int buf, int h) {
    short* bK = &smK[buf][w * 1024];
    short* bQ = &smQ[buf][w * 1024];
    const short* Kg = Kx + ((long)(b * Ln) + k0 + r0) * Dn + h * 64 + scol;
    gl_lds16(Kg, bK);
    gl_lds16(Kg + 8 * Dn, bK + 512);
    const short* Qg = Qm + ((long)(b * Ln) + q0 + r0) * Dn + h * 64 + scol;
    gl_lds16(Qg, bQ);
    gl_lds16(Qg + 8 * Dn, bQ + 512);
  };
  float wa[4][4] = {{0.f}};
  stage(0, 0);
  int cur = 0;
  for (int h = 0; h < NH; ++h) {
    bool pre = (h + 1 < NH);
    if (pre) stage(cur ^ 1, h + 1);
    __builtin_amdgcn_sched_barrier(0);
    if (pre) asm volatile("s_waitcnt vmcnt(4)" ::: "memory");
    else     asm volatile("s_waitcnt vmcnt(0)" ::: "memory");
    __builtin_amdgcn_s_barrier();
    __builtin_amdgcn_sched_barrier(0);
    const short* Kc = smK[cur];
    const short* Qc = smQ[cur];
    s16x8 qf0 = *(const s16x8*)(Qc + (w * 16 + lr) * 64 + ((lg * 8) ^ sw));
    s16x8 qf1 = *(const s16x8*)(Qc + (w * 16 + lr) * 64 + ((32 + lg * 8) ^ sw));
    float zq[4];
#pragma unroll
    for (int r = 0; r < 4; r++) zq[r] = smZ[h * 64 + w * 16 + lg * 4 + r];
#pragma unroll
    for (int n = 0; n < 4; n++) {
      const short* kr = Kc + (n * 16 + lr) * 64;
      s16x8 kf0 = *(const s16x8*)(kr + ((lg * 8) ^ sw));
      s16x8 kf1 = *(const s16x8*)(kr + ((32 + lg * 8) ^ sw));
      f32x4 S = {};
      S = __builtin_amdgcn_mfma_f32_16x16x32_bf16(qf0, kf0, S, 0, 0, 0);
      S = __builtin_amdgcn_mfma_f32_16x16x32_bf16(qf1, kf1, S, 0, 0, 0);
#pragma unroll
      for (int r = 0; r < 4; r++)
        wa[n][r] += __expf(S[r] * 0.125f + gv[n][r]) * zq[r];
    }
    __builtin_amdgcn_s_barrier();
    cur ^= 1;
  }
#pragma unroll
  for (int n = 0; n < 4; n++) {
    int k = k0 + n * 16 + lr;
#pragma unroll
    for (int r = 0; r < 4; r++) {
      int q = q0w + lg * 4 + r;
      float v = wa[n][r] * (1.0f / 16.0f);
      if (diag && k > q) v = 0.0f;
      aw[((long)b * Ln + q) * Ln + k] = v;
    }
  }
}

extern "C" void kernel_launch(void* const* d_in, const int* in_sizes, int n_in,
                              void* d_out, int out_size, void* d_ws, size_t ws_size,
                              hipStream_t stream) {
  const float* z    = (const float*)d_in[0];
  const float* ps   = (const float*)d_in[1];
  const float* Wq   = (const float*)d_in[2];
  const float* bq   = (const float*)d_in[3];
  const float* Wk   = (const float*)d_in[4];
  const float* bk   = (const float*)d_in[5];
  const float* Wv   = (const float*)d_in[6];
  const float* bv   = (const float*)d_in[7];
  const float* Wc   = (const float*)d_in[8];
  const float* gamma= (const float*)d_in[9];
  const float* Wg1  = (const float*)d_in[10];
  const float* bg1  = (const float*)d_in[11];
  const float* Wg2  = (const float*)d_in[12];
  const float* bg2  = (const float*)d_in[13];

  char* w = (char*)d_ws;
  auto alloc = [&](long bytes) { void* p = (void*)w; w += (bytes + 255) & ~255L; return p; };
  short* zb   = (short*)alloc(BLD * 2);                   // dead after mega GEMM
  short* pb   = (short*)alloc(BLD * 2);                   // dead after mega GEMM
  short* Wcat = (short*)alloc((long)(4 * Dn + HGn) * Dn * 2);
  short* Qp   = (short*)alloc(BLD * 2);
  short* Kp   = (short*)alloc(BLD * 2);
  short* Vtb  = (short*)alloc(BLD * 2);                   // V transposed: [b][h][d][L]
  short* Gk   = (short*)alloc(BLD * 2);
  short* Hfb  = (short*)alloc((long)Bn * Ln * HGn * 2);   // h in bf16
  float* zv   = (float*)alloc((long)Bn * NH * Ln * 4);
  short* Gb   = (short*)zb;   // 16.8MB bias slab aliases zb+pb (dead by then)

  float* outp = (float*)d_out;
  float* aw   = outp + BLD;

  // 1) fused casts (dst = zb|pb|Wcat contiguous)
  CastDesc cd;
  cd.src[0] = z;  cd.src[1] = ps; cd.src[2] = Wq; cd.src[3] = Wk;
  cd.src[4] = Wv; cd.src[5] = Wc; cd.src[6] = Wg1;
  long c0 = 0;
  cd.cum[0] = 0;
  cd.cum[1] = (c0 += BLD);
  cd.cum[2] = (c0 += BLD);
  cd.cum[3] = (c0 += (long)Dn * Dn);
  cd.cum[4] = (c0 += (long)Dn * Dn);
  cd.cum[5] = (c0 += (long)Dn * Dn);
  cd.cum[6] = (c0 += (long)Dn * Dn);
  cd.cum[7] = (c0 += (long)HGn * Dn);
  k_cast7<<<(int)(c0 / 1024), 256, 0, stream>>>(cd, zb);

  // 2) merged projections — 128x64 tile, 6 waves/SIMD
  k_gemm_mega<<<2176, 256, 0, stream>>>(zb, pb, Wcat, bq, bk, bv, bg1, Qp, Kp, Vtb, Gk, Hfb);

  // 3) gb (bf16, causal 128x64 panels) — diet structure, 6 waves/SIMD
  k_gemm_gbd<<<dim3(272, Bn), 256, 0, stream>>>(Gk, Kp, gamma, Gb);

  // 4) fused gate + RoPE (inline trig; K raw already consumed by gb)
  k_rope_fused<<<Bn * Ln, 256, 0, stream>>>(Qp, Kp, Hfb, Wg2, bg2);

  // 5) attention
  k_attn1<<<512, 256, 0, stream>>>(Qp, Kp, Vtb, Gb, outp, zv);
  k_attn2<<<dim3(32 * 32, Bn), 256, 0, stream>>>(Qp, Kp, Gb, zv, aw);
}